// Round 5
// baseline (399.388 us; speedup 1.0000x reference)
//
#include <hip/hip_runtime.h>
#include <hip/hip_cooperative_groups.h>

#define EPS 2e-5f

namespace cg = cooperative_groups;

using short8  = __attribute__((ext_vector_type(8))) short;
using floatx4 = __attribute__((ext_vector_type(4))) float;

// round-to-nearest-even fp32 -> bf16 bits
static __device__ inline unsigned short f2bf(float f) {
    unsigned u = __float_as_uint(f);
    u += 0x7fffu + ((u >> 16) & 1u);
    return (unsigned short)(u >> 16);
}

// ---------------------------------------------------------------------------
// Single cooperative mega-kernel; phases separated by grid.sync():
//  P1: zero stats; W1f bf16 B-frags [j][T16][ks3][lane][8]
//  P2: stage-1 MFMA (K=96) + pool+relu -> p1 bf16 [j][b][i*8+s] (coalesced
//      via LDS collect) + BN1 stats
//  P3: fold BN1 -> W2f frags; bias2[j][col]
//  P4: stage-2 MFMA (K=384, 2 m-tiles/wave) + bias + pool+relu
//      -> p2s bf16 [(j,l)][b][o32] (full-line stores via LDS) + BN2 stats
//  P5: fold BN2 into w3 (per-block LDS); stage-3 MFMA (K=96, max over l,
//      *2^-j, relu) -> act3 bf16 [j][b][o64] + BN3 stats
//  P6: fold BN3 into fw1 (per-block LDS B-frags per j); FC1 MFMA (5 planes,
//      K=64 each); fp32 LDS tail FC2/FC3 -> out (B,17)
// MFMA 16x16x32 bf16 layouts: A: m=l&15, k=(l>>4)*8+e; B: n=l&15, same k;
// C/D: row=(l>>4)*4+r, col=l&15.
// ---------------------------------------------------------------------------

struct P2S { float ls[32]; unsigned short ptile[32][16][8]; };
struct P3S { float a1[16]; float d1[16]; };
struct P4S { float ls[64]; unsigned short ptile[4][64][32]; };
struct P5S { float a2s[32], d2s[32], bias3s[64], ls[128];
             unsigned short W3s[6144]; unsigned short atile[32][64]; };
struct P6S { float a3s[64], d3s[64];
             float fw2s[256], fw3s[272], fb2s[16], fb3s[17], fb1f[16];
             float hbuf[4][16][17]; unsigned short W1s[5120]; };
union SmemU { P2S p2; P3S p3; P4S p4; P5S p5; P6S p6; };

__global__ void __launch_bounds__(256, 2)
mega(const float* __restrict__ x,   const float* __restrict__ w1,
     const float* __restrict__ w2,  const float* __restrict__ w3,
     const float* __restrict__ g1,  const float* __restrict__ b1,
     const float* __restrict__ g2,  const float* __restrict__ b2,
     const float* __restrict__ g3,  const float* __restrict__ b3,
     const float* __restrict__ fw1, const float* __restrict__ fb1,
     const float* __restrict__ fw2, const float* __restrict__ fb2,
     const float* __restrict__ fw3, const float* __restrict__ fb3,
     float* __restrict__ out,
     float* __restrict__ stats, unsigned short* __restrict__ W1f,
     unsigned short* __restrict__ W2f, float* __restrict__ bias2,
     unsigned short* __restrict__ p1, unsigned short* __restrict__ p2s,
     unsigned short* __restrict__ act3, int B) {
    cg::grid_group gg = cg::this_grid();
    __shared__ SmemU sm;
    const int tid  = threadIdx.x;
    const int bid  = blockIdx.x;
    const int nblk = gridDim.x;
    const int wav  = tid >> 6;
    const int lane = tid & 63;
    const int quad = lane >> 4, l15 = lane & 15;
    float* stats1 = stats;
    float* stats2 = stats + 32;
    float* stats3 = stats + 96;
    const float invN1 = 1.f / (float)(B * 72);
    const float invN2 = 1.f / (float)(B * 28);
    const float invN3 = 1.f / (float)(B * 5);

    // ---------------- P1: stats zero + W1f ----------------
    {
        int g0 = bid * 256 + tid;
        if (g0 < 256) stats[g0] = 0.f;
        for (int gid = g0; gid < 221184; gid += nblk * 256) {
            int j  = gid / 24576;
            int r  = gid % 24576;
            int T  = r / 1536;
            int r2 = r % 1536;
            int ks = r2 / 512;
            int r3 = r2 % 512;
            int ln = r3 >> 3, e = r3 & 7;
            int n  = T * 16 + (ln & 15);
            int kk = ks * 32 + (ln >> 4) * 8 + e;
            int o = n >> 4, t = n & 15;
            int i = kk >> 4, s = kk & 15;
            int h = 1 << j;
            int d = s - t;
            float val = 0.f;
            if (d >= -3 * h && d <= 3 * h) {
                float df = (float)d / (float)h;
                #pragma unroll
                for (int m = 0; m < 7; ++m) {
                    float hat = fmaxf(0.f, 1.f - fabsf(df - (float)(m - 3)));
                    val += w1[(o * 6 + i) * 7 + m] * hat;
                }
                val /= (float)h;
            }
            W1f[gid] = f2bf(val);
        }
    }
    gg.sync();

    // ---------------- P2: stage-1 MFMA + pool + BN1 stats ----------------
    {
        int t32max = B / 32;
        int msub = wav & 1, nh = wav >> 1;
        for (int wi = bid; wi < 9 * t32max; wi += nblk) {
            int j = wi / t32max, t32 = wi - j * t32max;
            __syncthreads();
            if (tid < 32) sm.p2.ls[tid] = 0.f;
            int mt = t32 * 2 + msub;
            floatx4 z = {0.f, 0.f, 0.f, 0.f};
            floatx4 acc[8];
            #pragma unroll
            for (int T = 0; T < 8; ++T) acc[T] = z;
            const float* xr = x + (size_t)(mt * 16 + l15) * 96;
            const short8* Bj = (const short8*)W1f + (size_t)(j * 16) * 3 * 64;
            #pragma unroll
            for (int ks = 0; ks < 3; ++ks) {
                int k0 = ks * 32 + quad * 8;
                floatx4 v0 = *(const floatx4*)(xr + k0);
                floatx4 v1 = *(const floatx4*)(xr + k0 + 4);
                short8 a;
                #pragma unroll
                for (int e = 0; e < 4; ++e) {
                    a[e]     = (short)f2bf(v0[e]);
                    a[e + 4] = (short)f2bf(v1[e]);
                }
                #pragma unroll
                for (int T = 0; T < 8; ++T) {
                    short8 b = Bj[((nh * 8 + T) * 3 + ks) * 64 + lane];
                    acc[T] = __builtin_amdgcn_mfma_f32_16x16x32_bf16(a, b, acc[T], 0, 0, 0);
                }
            }
            __syncthreads();
            int tp = l15;
            bool act = tp < 8;
            int tpe = tp & 7;
            int base = lane & 48;
            int c0 = base + max(2 * tpe - 1, 0);
            int c1 = base + 2 * tpe;
            int c2 = base + 2 * tpe + 1;
            int c3 = base + min(2 * tpe + 2, 15);
            int row_l = msub * 16 + quad * 4;
            #pragma unroll
            for (int T = 0; T < 8; ++T) {
                int o = nh * 8 + T;
                float psum = 0.f, pss = 0.f;
                #pragma unroll
                for (int r = 0; r < 4; ++r) {
                    float v  = acc[T][r];
                    float mx = fmaxf(fmaxf(__shfl(v, c0, 64), __shfl(v, c1, 64)),
                                     fmaxf(__shfl(v, c2, 64), __shfl(v, c3, 64)));
                    mx = fmaxf(mx, 0.f);
                    if (act) {
                        sm.p2.ptile[row_l + r][o][tp] = f2bf(mx);
                        psum += mx; pss += mx * mx;
                    }
                }
                #pragma unroll
                for (int m = 32; m >= 1; m >>= 1) {
                    psum += __shfl_xor(psum, m, 64);
                    pss  += __shfl_xor(pss,  m, 64);
                }
                if (lane == 0) {
                    atomicAdd(&sm.p2.ls[o], psum);
                    atomicAdd(&sm.p2.ls[16 + o], pss);
                }
            }
            __syncthreads();
            unsigned short* dst = p1 + ((size_t)j * B + t32 * 32) * 128;
            #pragma unroll
            for (int u = 0; u < 2; ++u) {
                int c = tid + u * 256;       // chunk: row*16 + o
                int rr = c >> 4, oo = c & 15;
                *(short8*)(dst + (size_t)rr * 128 + oo * 8) =
                    *(const short8*)&sm.p2.ptile[rr][oo][0];
            }
            if (tid < 16) {
                atomicAdd(&stats1[tid], sm.p2.ls[tid]);
                atomicAdd(&stats1[16 + tid], sm.p2.ls[16 + tid]);
            }
        }
    }
    gg.sync();

    // ---------------- P3: fold BN1 -> W2f + bias2 ----------------
    {
        if (tid < 16) {
            float mu  = stats1[tid] * invN1;
            float var = stats1[16 + tid] * invN1 - mu * mu;
            float rsg = rsqrtf(var + EPS);
            float a1  = g1[tid] * rsg;
            sm.p3.a1[tid] = a1;
            sm.p3.d1[tid] = b1[tid] - mu * a1;
        }
        __syncthreads();
        for (int gid = bid * 256 + tid; gid < 688128; gid += nblk * 256) {
            int j  = gid / 98304;
            int r  = gid % 98304;
            int T  = r / 6144;
            int r2 = r % 6144;
            int ks = r2 / 512;
            int r3 = r2 % 512;
            int ln = r3 >> 3, e = r3 & 7;
            int col = T * 16 + (ln & 15);
            int k   = ks * 32 + ((ln >> 4) << 3) + e;
            int o = col >> 3, t = col & 7;
            int ic = k >> 3, s = k & 7;
            int i = ic / 3, c = ic % 3;
            int h = 1 << j;
            int d = s - t;
            float raw = 0.f;
            if (d >= -h && d <= h) {
                float df = (float)d / (float)h;
                #pragma unroll
                for (int m = 0; m < 3; ++m) {
                    float hat = fmaxf(0.f, 1.f - fabsf(df - (float)(m - 1)));
                    raw += w2[((o * 16 + i) * 3 + c) * 3 + m] * hat;
                }
                raw /= (float)h;
            }
            W2f[gid] = f2bf(raw * sm.p3.a1[i]);
        }
        for (int e = bid * 4 + wav; e < 1792; e += nblk * 4) {
            int j = e >> 8, col = e & 255;
            int o = col >> 3, t = col & 7;
            int h = 1 << j;
            float s = 0.f;
            #pragma unroll
            for (int u = 0; u < 6; ++u) {
                int k = lane + 64 * u;
                int ic = k >> 3, ss = k & 7;
                int i = ic / 3, c = ic % 3;
                int d = ss - t;
                float raw = 0.f;
                if (d >= -h && d <= h) {
                    float df = (float)d / (float)h;
                    #pragma unroll
                    for (int m = 0; m < 3; ++m) {
                        float hat = fmaxf(0.f, 1.f - fabsf(df - (float)(m - 1)));
                        raw += w2[((o * 16 + i) * 3 + c) * 3 + m] * hat;
                    }
                    raw /= (float)h;
                }
                s = fmaf(raw, sm.p3.d1[i], s);
            }
            #pragma unroll
            for (int m = 32; m >= 1; m >>= 1) s += __shfl_xor(s, m, 64);
            if (lane == 0) bias2[e] = s;
        }
    }
    gg.sync();

    // ---------------- P4: stage-2 MFMA + pool + BN2 stats ----------------
    {
        int t64max = B / 64;
        int nh = wav & 1, mp = wav >> 1;
        for (int wi = bid; wi < 7 * t64max; wi += nblk) {
            int j = wi / t64max, t64 = wi - j * t64max;
            __syncthreads();
            if (tid < 64) sm.p4.ls[tid] = 0.f;
            int m0 = t64 * 64 + mp * 32;
            floatx4 z = {0.f, 0.f, 0.f, 0.f};
            floatx4 acc[2][8];
            #pragma unroll
            for (int mi = 0; mi < 2; ++mi)
                #pragma unroll
                for (int T = 0; T < 8; ++T) acc[mi][T] = z;
            const short8* Bj = (const short8*)W2f + (size_t)(j * 16) * 12 * 64;
            #pragma unroll
            for (int ks = 0; ks < 12; ++ks) {
                int k0 = ks * 32 + quad * 8;
                int i  = k0 / 24;
                int c  = (k0 - i * 24) >> 3;
                const unsigned short* ab =
                    p1 + ((size_t)(j + c) * B + m0 + l15) * 128 + i * 8;
                short8 a0 = *(const short8*)ab;
                short8 a1 = *(const short8*)(ab + 16 * 128);
                #pragma unroll
                for (int T = 0; T < 8; ++T) {
                    short8 b = Bj[((nh * 8 + T) * 12 + ks) * 64 + lane];
                    acc[0][T] = __builtin_amdgcn_mfma_f32_16x16x32_bf16(a0, b, acc[0][T], 0, 0, 0);
                    acc[1][T] = __builtin_amdgcn_mfma_f32_16x16x32_bf16(a1, b, acc[1][T], 0, 0, 0);
                }
            }
            __syncthreads();
            int tp  = lane & 7;
            bool act = tp < 4;
            int tpe = tp & 3;
            int base = lane & 56;
            int c0 = base + max(2 * tpe - 1, 0);
            int c1 = base + 2 * tpe;
            int c2 = base + 2 * tpe + 1;
            int c3 = base + min(2 * tpe + 2, 7);
            #pragma unroll
            for (int T = 0; T < 8; ++T) {
                int n = (nh * 8 + T) * 16 + l15;
                int o = n >> 3;
                float bias = bias2[j * 256 + n];
                float psum = 0.f, pss = 0.f;
                #pragma unroll
                for (int mi = 0; mi < 2; ++mi) {
                    int rbase = mp * 32 + mi * 16 + quad * 4;
                    #pragma unroll
                    for (int r = 0; r < 4; ++r) {
                        float v  = acc[mi][T][r] + bias;
                        float mx = fmaxf(fmaxf(__shfl(v, c0, 64), __shfl(v, c1, 64)),
                                         fmaxf(__shfl(v, c2, 64), __shfl(v, c3, 64)));
                        mx = fmaxf(mx, 0.f);
                        if (act) {
                            sm.p4.ptile[tp][rbase + r][o] = f2bf(mx);
                            psum += mx; pss += mx * mx;
                        }
                    }
                }
                #pragma unroll
                for (int m = 0; m < 5; ++m) {
                    int msk = (m < 3) ? (1 << m) : (1 << (m + 1));   // 1,2,4,16,32
                    psum += __shfl_xor(psum, msk, 64);
                    pss  += __shfl_xor(pss,  msk, 64);
                }
                if (lane == 0 || lane == 8) {
                    int oo = (nh * 8 + T) * 2 + (lane >> 3);
                    atomicAdd(&sm.p4.ls[oo], psum);
                    atomicAdd(&sm.p4.ls[32 + oo], pss);
                }
            }
            __syncthreads();
            #pragma unroll
            for (int u = 0; u < 4; ++u) {
                int c = tid + u * 256;       // chunk: tp*256 + row*4 + oq
                int tpp = c >> 8, rem = c & 255;
                int rr = rem >> 2, oq = rem & 3;
                *(short8*)(p2s + ((size_t)(j * 4 + tpp) * B + t64 * 64 + rr) * 32 + oq * 8) =
                    *(const short8*)&sm.p4.ptile[tpp][rr][oq * 8];
            }
            if (tid < 32) {
                atomicAdd(&stats2[tid], sm.p4.ls[tid]);
                atomicAdd(&stats2[32 + tid], sm.p4.ls[32 + tid]);
            }
        }
    }
    gg.sync();

    // ---------------- P5: fold BN2 + stage-3 MFMA + BN3 stats ----------------
    {
        if (tid < 32) {
            float mu  = stats2[tid] * invN2;
            float var = stats2[32 + tid] * invN2 - mu * mu;
            float rsg = rsqrtf(var + EPS);
            sm.p5.a2s[tid] = g2[tid] * rsg;
            sm.p5.d2s[tid] = b2[tid] - mu * sm.p5.a2s[tid];
        }
        __syncthreads();
        for (int idx = tid; idx < 6144; idx += 256) {
            int e  = idx & 7;
            int ln = (idx >> 3) & 63;
            int fs = idx >> 9;               // Tg*3+ks
            int Tg = fs / 3, ks = fs % 3;
            int n = Tg * 16 + (ln & 15);
            int i = (ln >> 4) * 8 + e;
            sm.p5.W3s[idx] = f2bf(w3[n * 96 + i * 3 + ks] * sm.p5.a2s[i]);
        }
        if (tid < 64) {
            float s = 0.f;
            for (int i = 0; i < 32; ++i)
                #pragma unroll
                for (int kk = 0; kk < 3; ++kk)
                    s = fmaf(w3[tid * 96 + i * 3 + kk], sm.p5.d2s[i], s);
            sm.p5.bias3s[tid] = s;
        }
        __syncthreads();
        int msub = wav & 1, nh = wav >> 1;
        short8 bf[2][3];
        #pragma unroll
        for (int T = 0; T < 2; ++T)
            #pragma unroll
            for (int ks = 0; ks < 3; ++ks)
                bf[T][ks] = *(const short8*)&sm.p5.W3s[(((nh * 2 + T) * 3 + ks) * 64 + lane) * 8];
        int t32max = B / 32;
        for (int wi = bid; wi < 5 * t32max; wi += nblk) {
            int j = wi / t32max, t32 = wi - j * t32max;
            __syncthreads();
            if (tid < 128) sm.p5.ls[tid] = 0.f;
            int m0 = (t32 * 2 + msub) * 16;
            floatx4 z = {0.f, 0.f, 0.f, 0.f};
            floatx4 acc[2][3];
            #pragma unroll
            for (int T = 0; T < 2; ++T)
                #pragma unroll
                for (int l = 0; l < 3; ++l) acc[T][l] = z;
            #pragma unroll
            for (int ks = 0; ks < 3; ++ks) {
                int jj = j + ks;
                #pragma unroll
                for (int l = 0; l < 3; ++l) {
                    short8 a = *(const short8*)(p2s +
                        ((size_t)(jj * 4 + l) * B + m0 + l15) * 32 + quad * 8);
                    #pragma unroll
                    for (int T = 0; T < 2; ++T)
                        acc[T][l] = __builtin_amdgcn_mfma_f32_16x16x32_bf16(a, bf[T][ks],
                                                                            acc[T][l], 0, 0, 0);
                }
            }
            __syncthreads();
            float inv = 1.f / (float)(1 << j);
            int row_l = msub * 16 + quad * 4;
            #pragma unroll
            for (int T = 0; T < 2; ++T) {
                int col = nh * 32 + T * 16 + l15;    // o
                float bias = sm.p5.bias3s[col];
                float psum = 0.f, pss = 0.f;
                #pragma unroll
                for (int r = 0; r < 4; ++r) {
                    float v = fmaxf(fmaxf(acc[T][0][r], acc[T][1][r]), acc[T][2][r]);
                    v = fmaxf((v + bias) * inv, 0.f);
                    sm.p5.atile[row_l + r][col] = f2bf(v);
                    psum += v; pss += v * v;
                }
                psum += __shfl_xor(psum, 16, 64); pss += __shfl_xor(pss, 16, 64);
                psum += __shfl_xor(psum, 32, 64); pss += __shfl_xor(pss, 32, 64);
                if (quad == 0) {
                    atomicAdd(&sm.p5.ls[col], psum);
                    atomicAdd(&sm.p5.ls[64 + col], pss);
                }
            }
            __syncthreads();
            {
                int rr = tid >> 3, oq = tid & 7;     // 256 chunks
                *(short8*)(act3 + ((size_t)j * B + t32 * 32 + rr) * 64 + oq * 8) =
                    *(const short8*)&sm.p5.atile[rr][oq * 8];
            }
            if (tid < 64) {
                atomicAdd(&stats3[tid], sm.p5.ls[tid]);
                atomicAdd(&stats3[64 + tid], sm.p5.ls[64 + tid]);
            }
        }
    }
    gg.sync();

    // ---------------- P6: fold BN3 + FC1 MFMA + FC2/FC3 tail ----------------
    {
        if (tid < 64) {
            float mu  = stats3[tid] * invN3;
            float var = stats3[64 + tid] * invN3 - mu * mu;
            float rsg = rsqrtf(var + EPS);
            sm.p6.a3s[tid] = g3[tid] * rsg;
            sm.p6.d3s[tid] = b3[tid] - mu * sm.p6.a3s[tid];
        }
        __syncthreads();
        for (int idx = tid; idx < 5120; idx += 256) {
            int e  = idx & 7;
            int ln = (idx >> 3) & 63;
            int fs = idx >> 9;               // j*2+ks
            int j = fs >> 1, ks = fs & 1;
            int n = ln & 15;
            int o = ks * 32 + (ln >> 4) * 8 + e;
            sm.p6.W1s[idx] = f2bf(fw1[n * 320 + o * 5 + j] * sm.p6.a3s[o]);
        }
        if (tid < 256) sm.p6.fw2s[tid] = fw2[tid];
        for (int idx = tid; idx < 272; idx += 256) sm.p6.fw3s[idx] = fw3[idx];
        if (tid < 16) sm.p6.fb2s[tid] = fb2[tid];
        if (tid < 17) sm.p6.fb3s[tid] = fb3[tid];
        if (tid >= 32 && tid < 48) {
            int f = tid - 32;
            float s = fb1[f];
            for (int o = 0; o < 64; ++o) {
                float dd = sm.p6.d3s[o];
                #pragma unroll
                for (int jj = 0; jj < 5; ++jj)
                    s = fmaf(fw1[f * 320 + o * 5 + jj], dd, s);
            }
            sm.p6.fb1f[f] = s;
        }
        __syncthreads();
        for (int tq = bid; tq < B / 64; tq += nblk) {
            int mt = tq * 4 + wav;
            floatx4 acc = {0.f, 0.f, 0.f, 0.f};
            #pragma unroll
            for (int j = 0; j < 5; ++j)
                #pragma unroll
                for (int ks = 0; ks < 2; ++ks) {
                    short8 a = *(const short8*)(act3 +
                        ((size_t)j * B + mt * 16 + l15) * 64 + ks * 32 + quad * 8);
                    short8 b = *(const short8*)&sm.p6.W1s[((j * 2 + ks) * 64 + lane) * 8];
                    acc = __builtin_amdgcn_mfma_f32_16x16x32_bf16(a, b, acc, 0, 0, 0);
                }
            #pragma unroll
            for (int r = 0; r < 4; ++r)
                sm.p6.hbuf[wav][quad * 4 + r][l15] = acc[r] + sm.p6.fb1f[l15];
            __syncthreads();
            if (lane < 16) {
                int row = l15;
                float hv[16];
                #pragma unroll
                for (int n = 0; n < 16; ++n) hv[n] = sm.p6.hbuf[wav][row][n];
                float h2[16];
                #pragma unroll
                for (int f2 = 0; f2 < 16; ++f2) {
                    float s = sm.p6.fb2s[f2];
                    #pragma unroll
                    for (int n = 0; n < 16; ++n) s = fmaf(sm.p6.fw2s[f2 * 16 + n], hv[n], s);
                    h2[f2] = s;
                }
                float* orow = out + (size_t)(mt * 16 + row) * 17;
                #pragma unroll
                for (int f3 = 0; f3 < 17; ++f3) {
                    float s = sm.p6.fb3s[f3];
                    #pragma unroll
                    for (int n = 0; n < 16; ++n) s = fmaf(sm.p6.fw3s[f3 * 16 + n], h2[n], s);
                    orow[f3] = s;
                }
            }
            __syncthreads();
        }
    }
}

extern "C" void kernel_launch(void* const* d_in, const int* in_sizes, int n_in,
                              void* d_out, int out_size, void* d_ws, size_t ws_size,
                              hipStream_t stream) {
    (void)n_in; (void)out_size; (void)ws_size;
    const float* x   = (const float*)d_in[0];
    const float* w1  = (const float*)d_in[1];
    const float* w2  = (const float*)d_in[2];
    const float* w3  = (const float*)d_in[3];
    const float* g1  = (const float*)d_in[4];
    const float* b1  = (const float*)d_in[5];
    const float* g2  = (const float*)d_in[6];
    const float* b2  = (const float*)d_in[7];
    const float* g3  = (const float*)d_in[8];
    const float* b3  = (const float*)d_in[9];
    const float* fw1 = (const float*)d_in[10];
    const float* fb1 = (const float*)d_in[11];
    const float* fw2 = (const float*)d_in[12];
    const float* fb2 = (const float*)d_in[13];
    const float* fw3 = (const float*)d_in[14];
    const float* fb3 = (const float*)d_in[15];
    float* out = (float*)d_out;

    int B = in_sizes[0] / 96;                 // 4096

    char* wsb = (char*)d_ws;
    float*          stats = (float*)wsb;                      // 256 f
    unsigned short* W1f   = (unsigned short*)(wsb + 1024);    // 221184 us
    unsigned short* W2f   = W1f + 221184;                     // 688128 us
    float*          bias2 = (float*)(W2f + 688128);           // 1792 f
    unsigned short* p1    = (unsigned short*)(bias2 + 1792);  // 9*B*128 us
    unsigned short* p2s   = p1 + (size_t)9 * B * 128;         // 28*B*32 us
    unsigned short* act3  = p2s + (size_t)28 * B * 32;        // 5*B*64 us

    int maxPerCU = 0;
    hipOccupancyMaxActiveBlocksPerMultiprocessor(&maxPerCU, (const void*)mega, 256, 0);
    if (maxPerCU < 1) maxPerCU = 1;
    int numCU = 0;
    hipDeviceGetAttribute(&numCU, hipDeviceAttributeMultiprocessorCount, 0);
    if (numCU <= 0) numCU = 256;
    int NB = maxPerCU * numCU;
    if (NB > 512) NB = 512;

    void* kargs[] = {
        (void*)&x, (void*)&w1, (void*)&w2, (void*)&w3,
        (void*)&g1, (void*)&b1, (void*)&g2, (void*)&b2,
        (void*)&g3, (void*)&b3, (void*)&fw1, (void*)&fb1,
        (void*)&fw2, (void*)&fb2, (void*)&fw3, (void*)&fb3,
        (void*)&out, (void*)&stats, (void*)&W1f, (void*)&W2f,
        (void*)&bias2, (void*)&p1, (void*)&p2s, (void*)&act3, (void*)&B
    };
    hipLaunchCooperativeKernel((void*)mega, dim3(NB), dim3(256), kargs, 0, stream);
}

// Round 6
// 296.169 us; speedup vs baseline: 1.3485x; 1.3485x over previous
//
#include <hip/hip_runtime.h>

#define EPS 2e-5f

using short8  = __attribute__((ext_vector_type(8))) short;
using short4v = __attribute__((ext_vector_type(4))) short;
using floatx4 = __attribute__((ext_vector_type(4))) float;

// round-to-nearest-even fp32 -> bf16 bits
static __device__ inline unsigned short f2bf(float f) {
    unsigned u = __float_as_uint(f);
    u += 0x7fffu + ((u >> 16) & 1u);
    return (unsigned short)(u >> 16);
}

// ---------------------------------------------------------------------------
// 4-kernel pipeline, no cooperative sync (grid.sync costs ~60us -> avoided),
// no weight-staging kernels (hat-resample = 2-tap lerp, regenerated in-block),
// no global stats atomics (per-block partials, reduced by the consumer).
// MFMA 16x16x32 bf16 layouts: A[m][k]: m=l&15, k=(l>>4)*8+e; B[k][n]: n=l&15;
// C/D: row=(l>>4)*4+r, col=l&15.
//   K1: stage-1. batch-as-A (x direct), weights-as-B gen'd in regs from LDS w1.
//       pool(16->8)+relu via shfl -> p1 bf16 [j][b][i*8+s]; partials1[288][32].
//   K2: reduce partials1 -> fold BN1; weights-as-A (12 frags from LDS w2),
//       batch-as-B from p1; pool(8->4)+relu via LDS -> p2s bf16 [(j,tp)][b][o32];
//       partials2[448][64].
//   K3: reduce partials2 -> fold BN2 into w3 (LDS); weights-as-A (3 frags),
//       B from p2s; max over l, *2^-j, relu -> act3 bf16 [j][b][o64] (direct
//       8B stores); partials3[160][128].
//   K4: reduce partials3 -> fold BN3 into fw1 (LDS B-frags); FC1 MFMA;
//       fp32 LDS tail FC2/FC3 -> out (B,17).
// ---------------------------------------------------------------------------

__global__ void __launch_bounds__(256) k1(const float* __restrict__ x,
                                          const float* __restrict__ w1,
                                          unsigned short* __restrict__ p1,
                                          float* __restrict__ partials1,
                                          int B) {
    __shared__ float w1s[672];
    __shared__ float ls[32];
    __shared__ unsigned short ptile[32][16][8];
    int tid = threadIdx.x, j = blockIdx.y;
    int wav = tid >> 6, lane = tid & 63;
    int quad = lane >> 4, l15 = lane & 15;
    int msub = wav & 1, nh = wav >> 1;
    for (int idx = tid; idx < 672; idx += 256) w1s[idx] = w1[idx];
    if (tid < 32) ls[tid] = 0.f;
    __syncthreads();
    int h = 1 << j;
    float hInv = 1.f / (float)h;
    // gen this wave's 24 B-frags (o=nh*8+T, t=l15) via 2-tap lerp
    short8 bf[8][3];
    #pragma unroll
    for (int T = 0; T < 8; ++T) {
        int o = nh * 8 + T;
        #pragma unroll
        for (int ks = 0; ks < 3; ++ks) {
            short8 v;
            #pragma unroll
            for (int e = 0; e < 8; ++e) {
                int k = ks * 32 + quad * 8 + e;
                int i = k >> 4, s = k & 15;
                int d = s - l15;
                float val = 0.f;
                if (d >= -3 * h && d <= 3 * h) {
                    float u = (float)d * hInv + 3.f;
                    int m0 = (int)u;
                    float f = u - (float)m0;
                    int m1 = min(m0 + 1, 6);
                    const float* wr = &w1s[(o * 6 + i) * 7];
                    val = (wr[m0] * (1.f - f) + wr[m1] * f) * hInv;
                }
                v[e] = (short)f2bf(val);
            }
            bf[T][ks] = v;
        }
    }
    int tp = l15;
    bool act = tp < 8;
    int tpe = tp & 7;
    int base = lane & 48;
    int c0 = base + max(2 * tpe - 1, 0);
    int c1 = base + 2 * tpe;
    int c2 = base + 2 * tpe + 1;
    int c3 = base + min(2 * tpe + 2, 15);
    for (int it = 0; it < 4; ++it) {
        int t32 = blockIdx.x * 4 + it;
        int mt  = t32 * 2 + msub;
        floatx4 z = {0.f, 0.f, 0.f, 0.f};
        floatx4 acc[8];
        #pragma unroll
        for (int T = 0; T < 8; ++T) acc[T] = z;
        const float* xr = x + (size_t)(mt * 16 + l15) * 96;
        #pragma unroll
        for (int ks = 0; ks < 3; ++ks) {
            int k0 = ks * 32 + quad * 8;
            floatx4 v0 = *(const floatx4*)(xr + k0);
            floatx4 v1 = *(const floatx4*)(xr + k0 + 4);
            short8 a;
            #pragma unroll
            for (int e = 0; e < 4; ++e) {
                a[e]     = (short)f2bf(v0[e]);
                a[e + 4] = (short)f2bf(v1[e]);
            }
            #pragma unroll
            for (int T = 0; T < 8; ++T)
                acc[T] = __builtin_amdgcn_mfma_f32_16x16x32_bf16(a, bf[T][ks], acc[T], 0, 0, 0);
        }
        __syncthreads();                     // ptile reuse guard
        int row_l = msub * 16 + quad * 4;
        #pragma unroll
        for (int T = 0; T < 8; ++T) {
            int o = nh * 8 + T;
            float psum = 0.f, pss = 0.f;
            #pragma unroll
            for (int r = 0; r < 4; ++r) {
                float v  = acc[T][r];
                float mx = fmaxf(fmaxf(__shfl(v, c0, 64), __shfl(v, c1, 64)),
                                 fmaxf(__shfl(v, c2, 64), __shfl(v, c3, 64)));
                mx = fmaxf(mx, 0.f);
                if (act) {
                    ptile[row_l + r][o][tp] = f2bf(mx);
                    psum += mx; pss += mx * mx;
                }
            }
            #pragma unroll
            for (int m = 32; m >= 1; m >>= 1) {
                psum += __shfl_xor(psum, m, 64);
                pss  += __shfl_xor(pss,  m, 64);
            }
            if (lane == 0) {
                atomicAdd(&ls[o], psum);
                atomicAdd(&ls[16 + o], pss);
            }
        }
        __syncthreads();
        unsigned short* dst = p1 + ((size_t)j * B + t32 * 32) * 128;
        #pragma unroll
        for (int u = 0; u < 2; ++u) {
            int c = tid + u * 256;
            int rr = c >> 4, oo = c & 15;
            *(short8*)(dst + (size_t)rr * 128 + oo * 8) = *(const short8*)&ptile[rr][oo][0];
        }
    }
    __syncthreads();
    if (tid < 32) partials1[(size_t)(blockIdx.y * 32 + blockIdx.x) * 32 + tid] = ls[tid];
}

__global__ void __launch_bounds__(256) k2(const unsigned short* __restrict__ p1,
                                          const float* __restrict__ w2,
                                          const float* __restrict__ g1,
                                          const float* __restrict__ b1,
                                          const float* __restrict__ partials1,
                                          unsigned short* __restrict__ p2s,
                                          float* __restrict__ partials2,
                                          int B) {
    __shared__ float w2s[4608];
    __shared__ float red[8][32];
    __shared__ float st1[32];
    __shared__ float a1s[16], d1s[16];
    __shared__ float wt[4][2][16][17];
    __shared__ float wbias[4][16];
    __shared__ unsigned short pt[4 * 32 * 8];
    __shared__ float ls2[64];
    int tid = threadIdx.x;
    int w = tid >> 6, lane = tid & 63;
    int quad = lane >> 4, l15 = lane & 15;
    int j = blockIdx.z, cs = blockIdx.y;
    float invN1 = 1.f / (float)(B * 72);
    for (int idx = tid; idx < 4608; idx += 256) w2s[idx] = w2[idx];
    {
        int ch = tid & 31, grp = tid >> 5;
        float s = 0.f;
        for (int g = grp; g < 288; g += 8) s += partials1[(size_t)g * 32 + ch];
        red[grp][ch] = s;
    }
    if (tid < 64) ls2[tid] = 0.f;
    __syncthreads();
    if (tid < 32) {
        float s = 0.f;
        #pragma unroll
        for (int g = 0; g < 8; ++g) s += red[g][tid];
        st1[tid] = s;
    }
    __syncthreads();
    if (tid < 16) {
        float mu  = st1[tid] * invN1;
        float var = st1[16 + tid] * invN1 - mu * mu;
        float rs  = rsqrtf(var + EPS);
        a1s[tid] = g1[tid] * rs;
        d1s[tid] = b1[tid] - mu * a1s[tid];
    }
    __syncthreads();
    int h = 1 << j;
    float hInv = 1.f / (float)h;
    int n = cs * 64 + w * 16 + l15;
    int o = n >> 3, t = n & 7;
    float biasacc = 0.f;
    short8 af[12];
    #pragma unroll
    for (int ks = 0; ks < 12; ++ks) {
        int ic = ks * 4 + quad;
        int i = ic / 3, c = ic - i * 3;
        const float* wr = &w2s[((o * 16 + i) * 3 + c) * 3];
        short8 v;
        #pragma unroll
        for (int e = 0; e < 8; ++e) {
            int d = e - t;
            float raw = 0.f;
            if (d >= -h && d <= h) {
                float u = (float)d * hInv + 1.f;
                int m0 = (int)u;
                float f = u - (float)m0;
                int m1 = min(m0 + 1, 2);
                raw = (wr[m0] * (1.f - f) + wr[m1] * f) * hInv;
            }
            v[e] = (short)f2bf(raw * a1s[i]);
            biasacc = fmaf(raw, d1s[i], biasacc);
        }
        af[ks] = v;
    }
    biasacc += __shfl_xor(biasacc, 16, 64);
    biasacc += __shfl_xor(biasacc, 32, 64);
    if (quad == 0) wbias[w][l15] = biasacc;
    __syncthreads();
    float ps[2] = {0.f, 0.f}, pq[2] = {0.f, 0.f};
    int lo = max(0, 2 * quad - 1), hi = min(7, 2 * quad + 2);
    for (int it = 0; it < 8; ++it) {
        int b0 = (blockIdx.x * 16 + it * 2) * 16;
        floatx4 accA = {0.f, 0.f, 0.f, 0.f};
        floatx4 accB = {0.f, 0.f, 0.f, 0.f};
        #pragma unroll
        for (int ks = 0; ks < 12; ++ks) {
            int ic = ks * 4 + quad;
            int i = ic / 3, c = ic - i * 3;
            const unsigned short* pr = p1 + ((size_t)(j + c) * B + b0 + l15) * 128 + i * 8;
            short8 bA = *(const short8*)pr;
            short8 bB = *(const short8*)(pr + 16 * 128);
            accA = __builtin_amdgcn_mfma_f32_16x16x32_bf16(af[ks], bA, accA, 0, 0, 0);
            accB = __builtin_amdgcn_mfma_f32_16x16x32_bf16(af[ks], bB, accB, 0, 0, 0);
        }
        __syncthreads();                     // wt/pt reuse guard
        #pragma unroll
        for (int r = 0; r < 4; ++r) {
            float br = wbias[w][quad * 4 + r];
            wt[w][0][quad * 4 + r][l15] = accA[r] + br;
            wt[w][1][quad * 4 + r][l15] = accB[r] + br;
        }
        __syncthreads();
        #pragma unroll
        for (int s_ = 0; s_ < 2; ++s_)
            #pragma unroll
            for (int u = 0; u < 2; ++u) {
                float m = -1e30f;
                for (int t_ = lo; t_ <= hi; ++t_) m = fmaxf(m, wt[w][s_][u * 8 + t_][l15]);
                float v = fmaxf(m, 0.f);
                pt[(quad * 32 + s_ * 16 + l15) * 8 + w * 2 + u] = f2bf(v);
                ps[u] += v; pq[u] += v * v;
            }
        __syncthreads();
        {
            int tpp = tid >> 6, rem = tid & 63;
            int bL = rem >> 1, og = rem & 1;
            *(short4v*)(p2s + ((size_t)(j * 4 + tpp) * B + b0 + bL) * 32 + cs * 8 + og * 4) =
                *(const short4v*)&pt[(tpp * 32 + bL) * 8 + og * 4];
        }
    }
    #pragma unroll
    for (int m = 1; m <= 32; m <<= 1) {
        #pragma unroll
        for (int u = 0; u < 2; ++u) {
            ps[u] += __shfl_xor(ps[u], m, 64);
            pq[u] += __shfl_xor(pq[u], m, 64);
        }
    }
    if (lane == 0) {
        int o0 = cs * 8 + w * 2;
        #pragma unroll
        for (int u = 0; u < 2; ++u) {
            ls2[(o0 + u) * 2]     = ps[u];
            ls2[(o0 + u) * 2 + 1] = pq[u];
        }
    }
    __syncthreads();
    int bid = blockIdx.x + 16 * (cs + 4 * j);
    if (tid < 64) partials2[(size_t)bid * 64 + tid] = ls2[tid];
}

__global__ void __launch_bounds__(256) k3(const unsigned short* __restrict__ p2s,
                                          const float* __restrict__ w3,
                                          const float* __restrict__ g2,
                                          const float* __restrict__ b2,
                                          const float* __restrict__ partials2,
                                          unsigned short* __restrict__ act3,
                                          float* __restrict__ partials3,
                                          int B) {
    __shared__ float w3s[6144];
    __shared__ float red[4][64];
    __shared__ float st2[64];
    __shared__ float a2s[32], d2s[32];
    __shared__ float ls3[128];
    int tid = threadIdx.x;
    int wav = tid >> 6, lane = tid & 63;
    int quad = lane >> 4, l15 = lane & 15;
    int j = blockIdx.y;
    float invN2 = 1.f / (float)(B * 28);
    for (int idx = tid; idx < 6144; idx += 256) w3s[idx] = w3[idx];
    {
        int ch = tid & 63, grp = tid >> 6;
        float s = 0.f;
        for (int g = grp; g < 448; g += 4) s += partials2[(size_t)g * 64 + ch];
        red[grp][ch] = s;
    }
    __syncthreads();
    if (tid < 64) st2[tid] = red[0][tid] + red[1][tid] + red[2][tid] + red[3][tid];
    __syncthreads();
    if (tid < 32) {
        float mu  = st2[tid * 2] * invN2;
        float var = st2[tid * 2 + 1] * invN2 - mu * mu;
        float rs  = rsqrtf(var + EPS);
        a2s[tid] = g2[tid] * rs;
        d2s[tid] = b2[tid] - mu * a2s[tid];
    }
    __syncthreads();
    int og = wav;
    int o  = og * 16 + l15;
    float biasacc = 0.f;
    short8 af[3];
    #pragma unroll
    for (int kf = 0; kf < 3; ++kf) {
        short8 v;
        #pragma unroll
        for (int e = 0; e < 8; ++e) {
            int i = quad * 8 + e;
            float raw = w3s[o * 96 + i * 3 + kf];
            v[e] = (short)f2bf(raw * a2s[i]);
            biasacc = fmaf(raw, d2s[i], biasacc);
        }
        af[kf] = v;
    }
    biasacc += __shfl_xor(biasacc, 16, 64);
    biasacc += __shfl_xor(biasacc, 32, 64);
    float brow[4];
    #pragma unroll
    for (int r = 0; r < 4; ++r) brow[r] = __shfl(biasacc, quad * 4 + r, 64);
    float inv = 1.f / (float)(1 << j);
    float ps[4] = {0.f, 0.f, 0.f, 0.f}, pq[4] = {0.f, 0.f, 0.f, 0.f};
    for (int it = 0; it < 8; ++it) {
        int b0 = (blockIdx.x * 8 + it) * 16;
        floatx4 aL0 = {0.f, 0.f, 0.f, 0.f};
        floatx4 aL1 = {0.f, 0.f, 0.f, 0.f};
        floatx4 aL2 = {0.f, 0.f, 0.f, 0.f};
        #pragma unroll
        for (int c = 0; c < 3; ++c) {
            const unsigned short* prb = p2s + ((size_t)(j + c) * 4 * B + b0 + l15) * 32 + quad * 8;
            short8 b0f = *(const short8*)prb;
            short8 b1f = *(const short8*)(prb + (size_t)B * 32);
            short8 b2f = *(const short8*)(prb + (size_t)2 * B * 32);
            aL0 = __builtin_amdgcn_mfma_f32_16x16x32_bf16(af[c], b0f, aL0, 0, 0, 0);
            aL1 = __builtin_amdgcn_mfma_f32_16x16x32_bf16(af[c], b1f, aL1, 0, 0, 0);
            aL2 = __builtin_amdgcn_mfma_f32_16x16x32_bf16(af[c], b2f, aL2, 0, 0, 0);
        }
        short4v pk;
        #pragma unroll
        for (int r = 0; r < 4; ++r) {
            float vm = fmaxf(fmaxf(aL0[r], aL1[r]), aL2[r]);
            float v  = fmaxf((vm + brow[r]) * inv, 0.f);
            pk[r] = (short)f2bf(v);
            ps[r] += v; pq[r] += v * v;
        }
        *(short4v*)(act3 + ((size_t)j * B + b0 + l15) * 64 + og * 16 + quad * 4) = pk;
    }
    #pragma unroll
    for (int m = 1; m <= 8; m <<= 1) {
        #pragma unroll
        for (int r = 0; r < 4; ++r) {
            ps[r] += __shfl_xor(ps[r], m, 64);
            pq[r] += __shfl_xor(pq[r], m, 64);
        }
    }
    if (l15 == 0) {
        #pragma unroll
        for (int r = 0; r < 4; ++r) {
            ls3[(og * 16 + quad * 4 + r) * 2]     = ps[r];
            ls3[(og * 16 + quad * 4 + r) * 2 + 1] = pq[r];
        }
    }
    __syncthreads();
    int bid = blockIdx.x + 32 * j;
    if (tid < 128) partials3[(size_t)bid * 128 + tid] = ls3[tid];
}

__global__ void __launch_bounds__(256) k4(const unsigned short* __restrict__ act3,
                                          const float* __restrict__ g3,
                                          const float* __restrict__ b3,
                                          const float* __restrict__ partials3,
                                          const float* __restrict__ fw1,
                                          const float* __restrict__ fb1,
                                          const float* __restrict__ fw2,
                                          const float* __restrict__ fb2,
                                          const float* __restrict__ fw3,
                                          const float* __restrict__ fb3,
                                          float* __restrict__ out,
                                          int B) {
    __shared__ float red[2][128];
    __shared__ float st3[128];
    __shared__ float a3s[64], d3s[64];
    __shared__ unsigned short W1s[5120];
    __shared__ float fw2s[256], fw3s[272], fb2s[16], fb3s[17], fb1f[16];
    __shared__ float hbuf[4][16][17];
    int tid = threadIdx.x;
    int wav = tid >> 6, lane = tid & 63;
    int quad = lane >> 4, l15 = lane & 15;
    float invN3 = 1.f / (float)(B * 5);
    {
        int ch = tid & 127, grp = tid >> 7;
        float s = 0.f;
        for (int g = grp; g < 160; g += 2) s += partials3[(size_t)g * 128 + ch];
        red[grp][ch] = s;
    }
    __syncthreads();
    if (tid < 128) st3[tid] = red[0][tid] + red[1][tid];
    __syncthreads();
    if (tid < 64) {
        float mu  = st3[tid * 2] * invN3;
        float var = st3[tid * 2 + 1] * invN3 - mu * mu;
        float rs  = rsqrtf(var + EPS);
        a3s[tid] = g3[tid] * rs;
        d3s[tid] = b3[tid] - mu * a3s[tid];
    }
    __syncthreads();
    for (int idx = tid; idx < 5120; idx += 256) {
        int e  = idx & 7;
        int ln = (idx >> 3) & 63;
        int fs = idx >> 9;
        int jj = fs >> 1, ks = fs & 1;
        int n = ln & 15;
        int o = ks * 32 + (ln >> 4) * 8 + e;
        W1s[idx] = f2bf(fw1[n * 320 + o * 5 + jj] * a3s[o]);
    }
    if (tid < 256) fw2s[tid] = fw2[tid];
    for (int idx = tid; idx < 272; idx += 256) fw3s[idx] = fw3[idx];
    if (tid < 16) fb2s[tid] = fb2[tid];
    if (tid < 17) fb3s[tid] = fb3[tid];
    if (tid >= 32 && tid < 48) {
        int f = tid - 32;
        float s = fb1[f];
        for (int o = 0; o < 64; ++o) {
            float dd = d3s[o];
            #pragma unroll
            for (int jj = 0; jj < 5; ++jj)
                s = fmaf(fw1[f * 320 + o * 5 + jj], dd, s);
        }
        fb1f[f] = s;
    }
    __syncthreads();
    int mt = blockIdx.x * 4 + wav;
    floatx4 acc = {0.f, 0.f, 0.f, 0.f};
    #pragma unroll
    for (int jj = 0; jj < 5; ++jj)
        #pragma unroll
        for (int ks = 0; ks < 2; ++ks) {
            short8 a = *(const short8*)(act3 +
                ((size_t)jj * B + mt * 16 + l15) * 64 + ks * 32 + quad * 8);
            short8 b = *(const short8*)&W1s[((jj * 2 + ks) * 64 + lane) * 8];
            acc = __builtin_amdgcn_mfma_f32_16x16x32_bf16(a, b, acc, 0, 0, 0);
        }
    #pragma unroll
    for (int r = 0; r < 4; ++r)
        hbuf[wav][quad * 4 + r][l15] = acc[r] + fb1f[l15];
    __syncthreads();
    if (lane < 16) {
        int row = l15;
        float hv[16];
        #pragma unroll
        for (int n = 0; n < 16; ++n) hv[n] = hbuf[wav][row][n];
        float h2[16];
        #pragma unroll
        for (int f2 = 0; f2 < 16; ++f2) {
            float s = fb2s[f2];
            #pragma unroll
            for (int n = 0; n < 16; ++n) s = fmaf(fw2s[f2 * 16 + n], hv[n], s);
            h2[f2] = s;
        }
        float* orow = out + (size_t)(mt * 16 + row) * 17;
        #pragma unroll
        for (int f3 = 0; f3 < 17; ++f3) {
            float s = fb3s[f3];
            #pragma unroll
            for (int n = 0; n < 16; ++n) s = fmaf(fw3s[f3 * 16 + n], h2[n], s);
            orow[f3] = s;
        }
    }
}

extern "C" void kernel_launch(void* const* d_in, const int* in_sizes, int n_in,
                              void* d_out, int out_size, void* d_ws, size_t ws_size,
                              hipStream_t stream) {
    (void)n_in; (void)out_size; (void)ws_size;
    const float* x   = (const float*)d_in[0];
    const float* w1  = (const float*)d_in[1];
    const float* w2  = (const float*)d_in[2];
    const float* w3  = (const float*)d_in[3];
    const float* g1  = (const float*)d_in[4];
    const float* b1  = (const float*)d_in[5];
    const float* g2  = (const float*)d_in[6];
    const float* b2  = (const float*)d_in[7];
    const float* g3  = (const float*)d_in[8];
    const float* b3  = (const float*)d_in[9];
    const float* fw1 = (const float*)d_in[10];
    const float* fb1 = (const float*)d_in[11];
    const float* fw2 = (const float*)d_in[12];
    const float* fb2 = (const float*)d_in[13];
    const float* fw3 = (const float*)d_in[14];
    const float* fb3 = (const float*)d_in[15];
    float* out = (float*)d_out;

    int B = in_sizes[0] / 96;                 // 4096

    char* wsb = (char*)d_ws;
    float* partials1 = (float*)wsb;                               // 288*32 f
    float* partials2 = partials1 + 288 * 32;                      // 448*64 f
    float* partials3 = partials2 + 448 * 64;                      // 160*128 f
    unsigned short* p1   = (unsigned short*)(partials3 + 160 * 128); // 9*B*128
    unsigned short* p2s  = p1 + (size_t)9 * B * 128;              // 28*B*32
    unsigned short* act3 = p2s + (size_t)28 * B * 32;             // 5*B*64

    k1<<<dim3(32, 9), 256, 0, stream>>>(x, w1, p1, partials1, B);
    k2<<<dim3(16, 4, 7), 256, 0, stream>>>(p1, w2, g1, b1, partials1, p2s, partials2, B);
    k3<<<dim3(32, 5), 256, 0, stream>>>(p2s, w3, g2, b2, partials2, act3, partials3, B);
    k4<<<B / 64, 256, 0, stream>>>(act3, g3, b3, partials3, fw1, fb1, fw2, fb2, fw3, fb3,
                                   out, B);
}

// Round 7
// 178.214 us; speedup vs baseline: 2.2411x; 1.6619x over previous
//
#include <hip/hip_runtime.h>

#define EPS 2e-5f

using short8  = __attribute__((ext_vector_type(8))) short;
using floatx4 = __attribute__((ext_vector_type(4))) float;

// round-to-nearest-even fp32 -> bf16 bits
static __device__ inline unsigned short f2bf(float f) {
    unsigned u = __float_as_uint(f);
    u += 0x7fffu + ((u >> 16) & 1u);
    return (unsigned short)(u >> 16);
}

// ---------------------------------------------------------------------------
// 6-kernel pipeline. Staged weight fragments (kS, k_bias), global-atomic BN
// stats (zeroed by kS), and LEAN epilogues: no shfl/bpermute chains — C-tile
// to padded LDS, per-thread pooling with b128 reads, register-accumulated
// stats, one LDS tree reduce, coalesced 16B global stores everywhere.
// MFMA 16x16x32 bf16 layouts: A[m][k]: m=l&15, k=(l>>4)*8+e; B[k][n]: n=l&15;
// C/D: row=(l>>4)*4+r, col=l&15.
//   kS    : zero stats[256]; W1f bf16 B-frags [(j*16+T)*3+ks][lane][8]
//   k1    : stage-1 GEMM (K=96), pool 16->8 + relu in LDS -> p1 [j][b][i*8+s]
//   k_bias: fold BN1 -> W2f frags [(j*16+T)*12+ks][lane][8]; bias2[j][col]
//   k2    : stage-2 GEMM (K=384, 2 m-tiles/wave), +bias, pool 8->4 + relu
//           (2-pass LDS epilogue) -> p2s [(j,tp)][b][o32]
//   k3    : fold BN2 into w3 in-regs; stage-3 GEMM (K=96), max over l, *2^-j,
//           relu -> act3 [j][b][o64] via LDS-collected coalesced stores
//   k4    : fold BN3 into fw1 (LDS); FC1 MFMA (K=320); fp32 tail FC2/FC3
// ---------------------------------------------------------------------------

__global__ void __launch_bounds__(256) kS(const float* __restrict__ w1,
                                          unsigned short* __restrict__ W1f,
                                          float* __restrict__ stats) {
    int gid = blockIdx.x * 256 + threadIdx.x;
    if (gid < 256) stats[gid] = 0.f;
    if (gid >= 221184) return;               // 9*16*3*512
    int j  = gid / 24576;
    int r  = gid % 24576;
    int T  = r / 1536;
    int r2 = r % 1536;
    int ks = r2 / 512;
    int r3 = r2 % 512;
    int ln = r3 >> 3, e = r3 & 7;
    int n  = T * 16 + (ln & 15);
    int kk = ks * 32 + (ln >> 4) * 8 + e;
    int o = n >> 4, t = n & 15;
    int i = kk >> 4, s = kk & 15;
    int h = 1 << j;
    int d = s - t;
    float val = 0.f;
    if (d >= -3 * h && d <= 3 * h) {
        float df = (float)d / (float)h;
        #pragma unroll
        for (int m = 0; m < 7; ++m) {
            float hat = fmaxf(0.f, 1.f - fabsf(df - (float)(m - 3)));
            val += w1[(o * 6 + i) * 7 + m] * hat;
        }
        val /= (float)h;
    }
    W1f[gid] = f2bf(val);
}

__global__ void __launch_bounds__(256) k1(const float* __restrict__ x,
                                          const unsigned short* __restrict__ W1f,
                                          unsigned short* __restrict__ p1,
                                          float* __restrict__ stats1, int B) {
    __shared__ float z[32 * 276];            // stride 276: pad -> 2-way-free banks
    __shared__ float lsS[256], lsQ[256];
    int tid = threadIdx.x, j = blockIdx.y;
    int wav = tid >> 6, lane = tid & 63;
    int quad = lane >> 4, l15 = lane & 15;
    int msub = wav & 1, nh = wav >> 1;
    int b0 = blockIdx.x * 32;
    floatx4 acc[8];
    #pragma unroll
    for (int T = 0; T < 8; ++T) acc[T] = floatx4{0.f, 0.f, 0.f, 0.f};
    const float* xr = x + (size_t)(b0 + msub * 16 + l15) * 96;
    const short8* Bj = (const short8*)W1f + (size_t)(j * 16) * 3 * 64;
    #pragma unroll
    for (int ks = 0; ks < 3; ++ks) {
        int k0 = ks * 32 + quad * 8;
        floatx4 v0 = *(const floatx4*)(xr + k0);
        floatx4 v1 = *(const floatx4*)(xr + k0 + 4);
        short8 a;
        #pragma unroll
        for (int e = 0; e < 4; ++e) {
            a[e]     = (short)f2bf(v0[e]);
            a[e + 4] = (short)f2bf(v1[e]);
        }
        #pragma unroll
        for (int T = 0; T < 8; ++T) {
            short8 b = Bj[((nh * 8 + T) * 3 + ks) * 64 + lane];
            acc[T] = __builtin_amdgcn_mfma_f32_16x16x32_bf16(a, b, acc[T], 0, 0, 0);
        }
    }
    #pragma unroll
    for (int T = 0; T < 8; ++T) {
        int col = (nh * 8 + T) * 16 + l15;
        int rb  = msub * 16 + quad * 4;
        #pragma unroll
        for (int r = 0; r < 4; ++r) z[(rb + r) * 276 + col] = acc[T][r];
    }
    __syncthreads();
    float psum = 0.f, pss = 0.f;
    #pragma unroll
    for (int i = 0; i < 2; ++i) {
        int u = tid + 256 * i;
        int row = u >> 4, o = u & 15;        // o == tid&15 both iters
        const float* zr = &z[row * 276 + o * 16];
        floatx4 q0 = ((const floatx4*)zr)[0];
        floatx4 q1 = ((const floatx4*)zr)[1];
        floatx4 q2 = ((const floatx4*)zr)[2];
        floatx4 q3 = ((const floatx4*)zr)[3];
        float t[16] = {q0[0], q0[1], q0[2], q0[3], q1[0], q1[1], q1[2], q1[3],
                       q2[0], q2[1], q2[2], q2[3], q3[0], q3[1], q3[2], q3[3]};
        short8 pk;
        #pragma unroll
        for (int tp = 0; tp < 8; ++tp) {
            int lo = (tp == 0) ? 0 : 2 * tp - 1;
            int hi = (tp == 7) ? 15 : 2 * tp + 2;
            float m = t[lo];
            for (int tt = lo + 1; tt <= hi; ++tt) m = fmaxf(m, t[tt]);
            m = fmaxf(m, 0.f);
            pk[tp] = (short)f2bf(m);
            psum += m; pss += m * m;
        }
        *(short8*)(p1 + ((size_t)j * B + b0 + row) * 128 + o * 8) = pk;
    }
    lsS[(tid & 15) * 16 + (tid >> 4)] = psum;
    lsQ[(tid & 15) * 16 + (tid >> 4)] = pss;
    __syncthreads();
    if (tid < 32) {
        int o = tid & 15;
        const float* src = (tid < 16) ? lsS : lsQ;
        float s = 0.f;
        #pragma unroll
        for (int g = 0; g < 16; ++g) s += src[o * 16 + g];
        atomicAdd(&stats1[(tid < 16 ? 0 : 16) + o], s);
    }
}

__global__ void __launch_bounds__(384) k_bias(const float* __restrict__ w2,
                                              const float* __restrict__ g1,
                                              const float* __restrict__ b1,
                                              const float* __restrict__ stats1,
                                              unsigned short* __restrict__ W2f,
                                              float* __restrict__ bias2,
                                              float invN1) {
    int blk = blockIdx.x;
    int j   = blk >> 8;        // 0..6
    int col = blk & 255;       // o*8 + t
    int o = col >> 3, t = col & 7;
    int k = threadIdx.x;       // (i*3+c)*8 + s
    int ic = k >> 3, s = k & 7;
    int i = ic / 3, c = ic % 3;
    float mu  = stats1[i] * invN1;
    float var = stats1[16 + i] * invN1 - mu * mu;
    float rsg = rsqrtf(var + EPS);
    float a1  = g1[i] * rsg;
    float d1  = b1[i] - mu * a1;
    int h = 1 << j;
    int d = s - t;
    float raw = 0.f;
    if (d >= -h && d <= h) {
        float df = (float)d / (float)h;
        #pragma unroll
        for (int m = 0; m < 3; ++m) {
            float hat = fmaxf(0.f, 1.f - fabsf(df - (float)(m - 1)));
            raw += w2[((o * 16 + i) * 3 + c) * 3 + m] * hat;
        }
        raw /= (float)h;
    }
    {
        int T    = col >> 4;
        int lane = (col & 15) + ((k >> 3) & 3) * 16;
        int ks   = k >> 5;
        int e    = k & 7;
        W2f[(((size_t)(j * 16 + T) * 12 + ks) * 64 + lane) * 8 + e] = f2bf(raw * a1);
    }
    __shared__ float red[384];
    red[k] = raw * d1;
    __syncthreads();
    if (k < 128) red[k] += red[k + 128] + red[k + 256];
    __syncthreads();
    for (int st = 64; st >= 1; st >>= 1) {
        if (k < st) red[k] += red[k + st];
        __syncthreads();
    }
    if (k == 0) bias2[j * 256 + col] = red[0];
}

__global__ void __launch_bounds__(256) k2(const unsigned short* __restrict__ p1,
                                          const unsigned short* __restrict__ W2f,
                                          const float* __restrict__ bias2,
                                          unsigned short* __restrict__ p2s,
                                          float* __restrict__ stats2, int B) {
    __shared__ float z[32 * 260];
    __shared__ unsigned short pt[4][64][40];
    __shared__ float lsS[512], lsQ[512];
    int tid = threadIdx.x, j = blockIdx.y;
    int wav = tid >> 6, lane = tid & 63;
    int quad = lane >> 4, l15 = lane & 15;
    int nh = wav & 1, mp = wav >> 1;
    int b0 = blockIdx.x * 64, m0 = b0 + mp * 32;
    floatx4 acc[2][8];
    #pragma unroll
    for (int mi = 0; mi < 2; ++mi)
        #pragma unroll
        for (int T = 0; T < 8; ++T) acc[mi][T] = floatx4{0.f, 0.f, 0.f, 0.f};
    const short8* Bj = (const short8*)W2f + (size_t)(j * 16) * 12 * 64;
    #pragma unroll
    for (int ks = 0; ks < 12; ++ks) {
        int icq = ks * 4 + quad;
        int i = icq / 3, c = icq - i * 3;
        const unsigned short* ap = p1 + ((size_t)(j + c) * B + m0 + l15) * 128 + i * 8;
        short8 a0 = *(const short8*)ap;
        short8 a1 = *(const short8*)(ap + 2048);     // +16 rows
        #pragma unroll
        for (int T = 0; T < 8; ++T) {
            short8 b = Bj[((nh * 8 + T) * 12 + ks) * 64 + lane];
            acc[0][T] = __builtin_amdgcn_mfma_f32_16x16x32_bf16(a0, b, acc[0][T], 0, 0, 0);
            acc[1][T] = __builtin_amdgcn_mfma_f32_16x16x32_bf16(a1, b, acc[1][T], 0, 0, 0);
        }
    }
    float biasv[8];
    #pragma unroll
    for (int T = 0; T < 8; ++T) biasv[T] = bias2[j * 256 + (nh * 8 + T) * 16 + l15];
    float psum[2] = {0.f, 0.f}, pss[2] = {0.f, 0.f};
    for (int pass = 0; pass < 2; ++pass) {
        __syncthreads();                     // z reuse guard
        if (mp == pass) {
            #pragma unroll
            for (int T = 0; T < 8; ++T) {
                int col = (nh * 8 + T) * 16 + l15;
                #pragma unroll
                for (int mi = 0; mi < 2; ++mi) {
                    int rb = mi * 16 + quad * 4;
                    #pragma unroll
                    for (int r = 0; r < 4; ++r)
                        z[(rb + r) * 260 + col] = acc[mi][T][r] + biasv[T];
                }
            }
        }
        __syncthreads();
        #pragma unroll
        for (int i2 = 0; i2 < 2; ++i2) {
            int u = tid + 256 * i2;
            int opr = u & 15, row = u >> 4;  // row 0..31; opr == tid&15
            const float* zr = &z[row * 260 + opr * 16];
            floatx4 q0 = ((const floatx4*)zr)[0];
            floatx4 q1 = ((const floatx4*)zr)[1];
            floatx4 q2 = ((const floatx4*)zr)[2];
            floatx4 q3 = ((const floatx4*)zr)[3];
            float ta[8] = {q0[0], q0[1], q0[2], q0[3], q1[0], q1[1], q1[2], q1[3]};
            float tb[8] = {q2[0], q2[1], q2[2], q2[3], q3[0], q3[1], q3[2], q3[3]};
            int rowg = pass * 32 + row;
            #pragma unroll
            for (int tp = 0; tp < 4; ++tp) {
                int lo = (tp == 0) ? 0 : 2 * tp - 1;
                int hi = (tp == 3) ? 7 : 2 * tp + 2;
                float m0v = ta[lo], m1v = tb[lo];
                for (int tt = lo + 1; tt <= hi; ++tt) {
                    m0v = fmaxf(m0v, ta[tt]); m1v = fmaxf(m1v, tb[tt]);
                }
                m0v = fmaxf(m0v, 0.f); m1v = fmaxf(m1v, 0.f);
                psum[0] += m0v; pss[0] += m0v * m0v;
                psum[1] += m1v; pss[1] += m1v * m1v;
                unsigned pk = (unsigned)f2bf(m0v) | ((unsigned)f2bf(m1v) << 16);
                *(unsigned*)&pt[tp][rowg][opr * 2] = pk;
            }
        }
    }
    {
        int o0 = 2 * (tid & 15), g = tid >> 4;
        lsS[o0 * 16 + g] = psum[0]; lsS[(o0 + 1) * 16 + g] = psum[1];
        lsQ[o0 * 16 + g] = pss[0];  lsQ[(o0 + 1) * 16 + g] = pss[1];
    }
    __syncthreads();
    #pragma unroll
    for (int tp = 0; tp < 4; ++tp) {
        int oct = tid & 3, row = (tid >> 2) & 63;
        *(short8*)(p2s + ((size_t)(j * 4 + tp) * B + b0 + row) * 32 + oct * 8) =
            *(const short8*)&pt[tp][row][oct * 8];
    }
    if (tid < 64) {
        int o = tid & 31;
        const float* src = (tid < 32) ? lsS : lsQ;
        float s = 0.f;
        #pragma unroll
        for (int g = 0; g < 16; ++g) s += src[o * 16 + g];
        atomicAdd(&stats2[(tid < 32 ? 0 : 32) + o], s);
    }
}

__global__ void __launch_bounds__(256) k3(const unsigned short* __restrict__ p2s,
                                          const float* __restrict__ w3,
                                          const float* __restrict__ g2,
                                          const float* __restrict__ b2,
                                          const float* __restrict__ stats2,
                                          unsigned short* __restrict__ act3,
                                          float* __restrict__ stats3,
                                          float invN2, int B) {
    __shared__ float a2s[32], d2s[32];
    __shared__ unsigned short atile[32][72];
    __shared__ float lsS[1024], lsQ[1024];
    int tid = threadIdx.x, j = blockIdx.y, b0 = blockIdx.x * 32;
    int og = tid >> 6, lane = tid & 63;
    int quad = lane >> 4, l15 = lane & 15;
    if (tid < 32) {
        float mu  = stats2[tid] * invN2;
        float var = stats2[32 + tid] * invN2 - mu * mu;
        float rs  = rsqrtf(var + EPS);
        a2s[tid] = g2[tid] * rs;
        d2s[tid] = b2[tid] - mu * a2s[tid];
    }
    __syncthreads();
    int o = og * 16 + l15;
    float biasacc = 0.f;
    short8 af[3];
    #pragma unroll
    for (int kf = 0; kf < 3; ++kf) {
        short8 v;
        #pragma unroll
        for (int e = 0; e < 8; ++e) {
            int i = quad * 8 + e;
            float raw = w3[o * 96 + i * 3 + kf];
            v[e] = (short)f2bf(raw * a2s[i]);
            biasacc = fmaf(raw, d2s[i], biasacc);
        }
        af[kf] = v;
    }
    biasacc += __shfl_xor(biasacc, 16, 64);
    biasacc += __shfl_xor(biasacc, 32, 64);
    float brow[4];
    #pragma unroll
    for (int r = 0; r < 4; ++r) brow[r] = __shfl(biasacc, quad * 4 + r, 64);
    float inv = 1.f / (float)(1 << j);
    float psum[4] = {0.f, 0.f, 0.f, 0.f}, pss[4] = {0.f, 0.f, 0.f, 0.f};
    #pragma unroll
    for (int bt = 0; bt < 2; ++bt) {
        int bb = b0 + bt * 16;
        floatx4 aL0 = {0.f, 0.f, 0.f, 0.f};
        floatx4 aL1 = {0.f, 0.f, 0.f, 0.f};
        floatx4 aL2 = {0.f, 0.f, 0.f, 0.f};
        #pragma unroll
        for (int c = 0; c < 3; ++c) {
            const unsigned short* base =
                p2s + ((size_t)((j + c) * 4) * B + bb + l15) * 32 + quad * 8;
            short8 f0 = *(const short8*)base;
            short8 f1 = *(const short8*)(base + (size_t)B * 32);
            short8 f2v = *(const short8*)(base + (size_t)2 * B * 32);
            aL0 = __builtin_amdgcn_mfma_f32_16x16x32_bf16(af[c], f0, aL0, 0, 0, 0);
            aL1 = __builtin_amdgcn_mfma_f32_16x16x32_bf16(af[c], f1, aL1, 0, 0, 0);
            aL2 = __builtin_amdgcn_mfma_f32_16x16x32_bf16(af[c], f2v, aL2, 0, 0, 0);
        }
        #pragma unroll
        for (int r = 0; r < 4; ++r) {
            float vm = fmaxf(fmaxf(aL0[r], aL1[r]), aL2[r]);
            float v  = fmaxf((vm + brow[r]) * inv, 0.f);
            atile[bt * 16 + l15][og * 16 + quad * 4 + r] = f2bf(v);
            psum[r] += v; pss[r] += v * v;
        }
    }
    #pragma unroll
    for (int r = 0; r < 4; ++r) {
        lsS[(og * 16 + quad * 4 + r) * 16 + l15] = psum[r];
        lsQ[(og * 16 + quad * 4 + r) * 16 + l15] = pss[r];
    }
    __syncthreads();
    {
        int row = tid >> 3, oct = tid & 7;
        *(short8*)(act3 + ((size_t)j * B + b0 + row) * 64 + oct * 8) =
            *(const short8*)&atile[row][oct * 8];
    }
    if (tid < 128) {
        int oo = tid & 63;
        const float* src = (tid < 64) ? lsS : lsQ;
        float s = 0.f;
        #pragma unroll
        for (int g = 0; g < 16; ++g) s += src[oo * 16 + g];
        atomicAdd(&stats3[(tid < 64 ? 0 : 64) + oo], s);
    }
}

__global__ void __launch_bounds__(64) k4(const unsigned short* __restrict__ act3,
                                         const float* __restrict__ g3,
                                         const float* __restrict__ b3,
                                         const float* __restrict__ stats3,
                                         const float* __restrict__ fw1,
                                         const float* __restrict__ fb1,
                                         const float* __restrict__ fw2,
                                         const float* __restrict__ fb2,
                                         const float* __restrict__ fw3,
                                         const float* __restrict__ fb3,
                                         float* __restrict__ out,
                                         float invN3, int B) {
    __shared__ float a3s[64], d3s[64];
    __shared__ unsigned short W1s[5120];
    __shared__ float fw2s[256], fw3s[272], fb2s[16], fb3s[17], fb1f[16], tmp[4][16];
    __shared__ float hbuf[16][17];
    int tid = threadIdx.x, lane = tid;
    int quad = lane >> 4, l15 = lane & 15;
    {
        float mu  = stats3[tid] * invN3;
        float var = stats3[64 + tid] * invN3 - mu * mu;
        float rs  = rsqrtf(var + EPS);
        a3s[tid] = g3[tid] * rs;
        d3s[tid] = b3[tid] - mu * a3s[tid];
    }
    __syncthreads();
    #pragma unroll 4
    for (int k = 0; k < 80; ++k) {
        int idx = tid + 64 * k;
        int e  = idx & 7;
        int ln = (idx >> 3) & 63;
        int fs = idx >> 9;
        int jj = fs >> 1, ks = fs & 1;
        int n = ln & 15;
        int oo = ks * 32 + (ln >> 4) * 8 + e;
        W1s[idx] = f2bf(fw1[n * 320 + oo * 5 + jj] * a3s[oo]);
    }
    #pragma unroll
    for (int k = 0; k < 4; ++k) fw2s[tid + 64 * k] = fw2[tid + 64 * k];
    for (int idx = tid; idx < 272; idx += 64) fw3s[idx] = fw3[idx];
    if (tid < 16) fb2s[tid] = fb2[tid];
    if (tid < 17) fb3s[tid] = fb3[tid];
    {
        int f = tid & 15, ch = tid >> 4;
        float s = 0.f;
        for (int u = 0; u < 80; ++u) {
            int n = ch * 80 + u;
            s = fmaf(fw1[f * 320 + n], d3s[n / 5], s);
        }
        tmp[ch][f] = s;
    }
    __syncthreads();
    if (tid < 16) fb1f[tid] = fb1[tid] + tmp[0][tid] + tmp[1][tid] + tmp[2][tid] + tmp[3][tid];
    __syncthreads();
    int mt = blockIdx.x;
    floatx4 acc = {0.f, 0.f, 0.f, 0.f};
    #pragma unroll
    for (int jj = 0; jj < 5; ++jj)
        #pragma unroll
        for (int ks = 0; ks < 2; ++ks) {
            short8 a = *(const short8*)(act3 +
                ((size_t)jj * B + mt * 16 + l15) * 64 + ks * 32 + quad * 8);
            short8 b = *(const short8*)&W1s[((jj * 2 + ks) * 64 + lane) * 8];
            acc = __builtin_amdgcn_mfma_f32_16x16x32_bf16(a, b, acc, 0, 0, 0);
        }
    #pragma unroll
    for (int r = 0; r < 4; ++r) hbuf[quad * 4 + r][l15] = acc[r] + fb1f[l15];
    __syncthreads();
    if (lane < 16) {
        int row = l15;
        float hv[16];
        #pragma unroll
        for (int n = 0; n < 16; ++n) hv[n] = hbuf[row][n];
        float h2[16];
        #pragma unroll
        for (int f2 = 0; f2 < 16; ++f2) {
            float s = fb2s[f2];
            #pragma unroll
            for (int n = 0; n < 16; ++n) s = fmaf(fw2s[f2 * 16 + n], hv[n], s);
            h2[f2] = s;
        }
        float* orow = out + (size_t)(mt * 16 + row) * 17;
        #pragma unroll
        for (int f3 = 0; f3 < 17; ++f3) {
            float s = fb3s[f3];
            #pragma unroll
            for (int n = 0; n < 16; ++n) s = fmaf(fw3s[f3 * 16 + n], h2[n], s);
            orow[f3] = s;
        }
    }
}

extern "C" void kernel_launch(void* const* d_in, const int* in_sizes, int n_in,
                              void* d_out, int out_size, void* d_ws, size_t ws_size,
                              hipStream_t stream) {
    (void)n_in; (void)out_size; (void)ws_size;
    const float* x   = (const float*)d_in[0];
    const float* w1  = (const float*)d_in[1];
    const float* w2  = (const float*)d_in[2];
    const float* w3  = (const float*)d_in[3];
    const float* g1  = (const float*)d_in[4];
    const float* b1  = (const float*)d_in[5];
    const float* g2  = (const float*)d_in[6];
    const float* b2  = (const float*)d_in[7];
    const float* g3  = (const float*)d_in[8];
    const float* b3  = (const float*)d_in[9];
    const float* fw1 = (const float*)d_in[10];
    const float* fb1 = (const float*)d_in[11];
    const float* fw2 = (const float*)d_in[12];
    const float* fb2 = (const float*)d_in[13];
    const float* fw3 = (const float*)d_in[14];
    const float* fb3 = (const float*)d_in[15];
    float* out = (float*)d_out;

    int B = in_sizes[0] / 96;                 // 4096

    char* wsb = (char*)d_ws;
    float*          stats = (float*)wsb;                      // 256 f
    unsigned short* W1f   = (unsigned short*)(wsb + 1024);    // 221184 us
    unsigned short* W2f   = W1f + 221184;                     // 688128 us
    float*          bias2 = (float*)(W2f + 688128);           // 1792 f
    unsigned short* p1    = (unsigned short*)(bias2 + 1792);  // 9*B*128 us
    unsigned short* p2s   = p1 + (size_t)9 * B * 128;         // 28*B*32 us
    unsigned short* act3  = p2s + (size_t)28 * B * 32;        // 5*B*64 us

    float* stats1 = stats;
    float* stats2 = stats + 32;
    float* stats3 = stats + 96;

    float invN1 = 1.f / (float)(B * 72);
    float invN2 = 1.f / (float)(B * 28);
    float invN3 = 1.f / (float)(B * 5);

    kS<<<864, 256, 0, stream>>>(w1, W1f, stats);
    k1<<<dim3(B / 32, 9), 256, 0, stream>>>(x, W1f, p1, stats1, B);
    k_bias<<<7 * 256, 384, 0, stream>>>(w2, g1, b1, stats1, W2f, bias2, invN1);
    k2<<<dim3(B / 64, 7), 256, 0, stream>>>(p1, W2f, bias2, p2s, stats2, B);
    k3<<<dim3(B / 32, 5), 256, 0, stream>>>(p2s, w3, g2, b2, stats2, act3, stats3,
                                            invN2, B);
    k4<<<B / 16, 64, 0, stream>>>(act3, g3, b3, stats3, fw1, fb1, fw2, fb2, fw3, fb3,
                                  out, invN3, B);
}

// Round 9
// 175.527 us; speedup vs baseline: 2.2754x; 1.0153x over previous
//
#include <hip/hip_runtime.h>

#define EPS 2e-5f

using short8  = __attribute__((ext_vector_type(8))) short;
using floatx4 = __attribute__((ext_vector_type(4))) float;

// round-to-nearest-even fp32 -> bf16 bits
static __device__ inline unsigned short f2bf(float f) {
    unsigned u = __float_as_uint(f);
    u += 0x7fffu + ((u >> 16) & 1u);
    return (unsigned short)(u >> 16);
}
static __device__ inline float bf2f(short s) {
    return __uint_as_float(((unsigned)(unsigned short)s) << 16);
}
static __device__ inline short8 scale8(short8 v, float sc) {
    short8 r;
    #pragma unroll
    for (int e = 0; e < 8; ++e) r[e] = (short)f2bf(bf2f(v[e]) * sc);
    return r;
}

// ---------------------------------------------------------------------------
// 5-kernel pipeline. Stats-independent weight staging in kS; BN folds in the
// consumers (k2: scale A-frags by a1[i] in-reg + bias from staged S; k3/k4:
// fold in LDS). LDS-tile epilogues, coalesced 16B stores, no shfl chains,
// no scattered global weight reads.
// NOTE (R8 bug): k2's bias2L LDS buffer is read cross-thread -> REQUIRES a
// __syncthreads() between write and read (wave skew race otherwise).
// MFMA 16x16x32 bf16 layouts: A[m][k]: m=l&15, k=(l>>4)*8+e; B[k][n]: n=l&15;
// C/D: row=(l>>4)*4+r, col=l&15.
// ---------------------------------------------------------------------------

__global__ void __launch_bounds__(256) kS(const float* __restrict__ w1,
                                          const float* __restrict__ w2,
                                          unsigned short* __restrict__ W1f,
                                          unsigned short* __restrict__ W2r,
                                          float* __restrict__ S,
                                          float* __restrict__ stats) {
    int gid = blockIdx.x * 256 + threadIdx.x;
    if (gid < 256) stats[gid] = 0.f;
    if (gid < 221184) {                      // W1f: 9*16*3*512
        int j  = gid / 24576;
        int r  = gid % 24576;
        int T  = r / 1536;
        int r2 = r % 1536;
        int ks = r2 / 512;
        int r3 = r2 % 512;
        int ln = r3 >> 3, e = r3 & 7;
        int n  = T * 16 + (ln & 15);
        int kk = ks * 32 + (ln >> 4) * 8 + e;
        int o = n >> 4, t = n & 15;
        int i = kk >> 4, s = kk & 15;
        int h = 1 << j;
        int d = s - t;
        float val = 0.f;
        if (d >= -3 * h && d <= 3 * h) {
            float df = (float)d / (float)h;
            #pragma unroll
            for (int m = 0; m < 7; ++m) {
                float hat = fmaxf(0.f, 1.f - fabsf(df - (float)(m - 3)));
                val += w1[(o * 6 + i) * 7 + m] * hat;
            }
            val /= (float)h;
        }
        W1f[gid] = f2bf(val);
    } else if (gid < 909312) {               // W2r: 7*16*12*512 raw frags
        int g  = gid - 221184;
        int fs = g >> 9;                     // (j*16+T)*12+ks
        int ln = (g >> 3) & 63, e = g & 7;
        int j  = fs / 192;
        int rm = fs % 192;
        int T  = rm / 12, ks = rm % 12;
        int col = T * 16 + (ln & 15);
        int k   = ks * 32 + (ln >> 4) * 8 + e;
        int o = col >> 3, t = col & 7;
        int ic = k >> 3, s = k & 7;
        int i = ic / 3, c = ic % 3;
        int h = 1 << j;
        int d = s - t;
        float raw = 0.f;
        if (d >= -h && d <= h) {
            float df = (float)d / (float)h;
            #pragma unroll
            for (int m = 0; m < 3; ++m) {
                float hat = fmaxf(0.f, 1.f - fabsf(df - (float)(m - 1)));
                raw += w2[((o * 16 + i) * 3 + c) * 3 + m] * hat;
            }
            raw /= (float)h;
        }
        W2r[g] = f2bf(raw);
    } else if (gid < 937984) {               // S: 7*16*256 = sum_{c,s} raw
        int g = gid - 909312;
        int j = g >> 12;
        int r = g & 4095;
        int i = r >> 8;
        int col = r & 255;
        int o = col >> 3, t = col & 7;
        int h = 1 << j;
        float acc = 0.f;
        #pragma unroll
        for (int c = 0; c < 3; ++c) {
            const float* wr = &w2[((o * 16 + i) * 3 + c) * 3];
            #pragma unroll
            for (int s = 0; s < 8; ++s) {
                int d = s - t;
                if (d >= -h && d <= h) {
                    float df = (float)d / (float)h;
                    float raw = 0.f;
                    #pragma unroll
                    for (int m = 0; m < 3; ++m) {
                        float hat = fmaxf(0.f, 1.f - fabsf(df - (float)(m - 1)));
                        raw += wr[m] * hat;
                    }
                    acc += raw / (float)h;
                }
            }
        }
        S[g] = acc;
    }
}

__global__ void __launch_bounds__(256) k1(const float* __restrict__ x,
                                          const unsigned short* __restrict__ W1f,
                                          unsigned short* __restrict__ p1,
                                          float* __restrict__ stats1, int B) {
    __shared__ float z[32 * 276];            // stride 276: 2-way-free banks
    __shared__ float lsS[256], lsQ[256];
    int tid = threadIdx.x, j = blockIdx.y;
    int wav = tid >> 6, lane = tid & 63;
    int quad = lane >> 4, l15 = lane & 15;
    int msub = wav & 1, nh = wav >> 1;
    int b0 = blockIdx.x * 32;
    floatx4 acc[8];
    #pragma unroll
    for (int T = 0; T < 8; ++T) acc[T] = floatx4{0.f, 0.f, 0.f, 0.f};
    const float* xr = x + (size_t)(b0 + msub * 16 + l15) * 96;
    const short8* Bj = (const short8*)W1f + (size_t)(j * 16) * 3 * 64;
    #pragma unroll
    for (int ks = 0; ks < 3; ++ks) {
        int k0 = ks * 32 + quad * 8;
        floatx4 v0 = *(const floatx4*)(xr + k0);
        floatx4 v1 = *(const floatx4*)(xr + k0 + 4);
        short8 a;
        #pragma unroll
        for (int e = 0; e < 4; ++e) {
            a[e]     = (short)f2bf(v0[e]);
            a[e + 4] = (short)f2bf(v1[e]);
        }
        #pragma unroll
        for (int T = 0; T < 8; ++T) {
            short8 b = Bj[((nh * 8 + T) * 3 + ks) * 64 + lane];
            acc[T] = __builtin_amdgcn_mfma_f32_16x16x32_bf16(a, b, acc[T], 0, 0, 0);
        }
    }
    #pragma unroll
    for (int T = 0; T < 8; ++T) {
        int col = (nh * 8 + T) * 16 + l15;
        int rb  = msub * 16 + quad * 4;
        #pragma unroll
        for (int r = 0; r < 4; ++r) z[(rb + r) * 276 + col] = acc[T][r];
    }
    __syncthreads();
    float psum = 0.f, pss = 0.f;
    #pragma unroll
    for (int i = 0; i < 2; ++i) {
        int u = tid + 256 * i;
        int row = u >> 4, o = u & 15;
        const float* zr = &z[row * 276 + o * 16];
        floatx4 q0 = ((const floatx4*)zr)[0];
        floatx4 q1 = ((const floatx4*)zr)[1];
        floatx4 q2 = ((const floatx4*)zr)[2];
        floatx4 q3 = ((const floatx4*)zr)[3];
        float t[16] = {q0[0], q0[1], q0[2], q0[3], q1[0], q1[1], q1[2], q1[3],
                       q2[0], q2[1], q2[2], q2[3], q3[0], q3[1], q3[2], q3[3]};
        short8 pk;
        #pragma unroll
        for (int tp = 0; tp < 8; ++tp) {
            int lo = (tp == 0) ? 0 : 2 * tp - 1;
            int hi = (tp == 7) ? 15 : 2 * tp + 2;
            float m = t[lo];
            for (int tt = lo + 1; tt <= hi; ++tt) m = fmaxf(m, t[tt]);
            m = fmaxf(m, 0.f);
            pk[tp] = (short)f2bf(m);
            psum += m; pss += m * m;
        }
        *(short8*)(p1 + ((size_t)j * B + b0 + row) * 128 + o * 8) = pk;
    }
    lsS[(tid & 15) * 16 + (tid >> 4)] = psum;
    lsQ[(tid & 15) * 16 + (tid >> 4)] = pss;
    __syncthreads();
    if (tid < 32) {
        int o = tid & 15;
        const float* src = (tid < 16) ? lsS : lsQ;
        float s = 0.f;
        #pragma unroll
        for (int g = 0; g < 16; ++g) s += src[o * 16 + g];
        atomicAdd(&stats1[(tid < 16 ? 0 : 16) + o], s);
    }
}

__global__ void __launch_bounds__(256) k2(const unsigned short* __restrict__ p1,
                                          const unsigned short* __restrict__ W2r,
                                          const float* __restrict__ S,
                                          const float* __restrict__ g1,
                                          const float* __restrict__ b1,
                                          const float* __restrict__ stats1,
                                          unsigned short* __restrict__ p2s,
                                          float* __restrict__ stats2,
                                          float invN1, int B) {
    __shared__ float z[32 * 260];
    __shared__ unsigned short pt[4][64][40];
    __shared__ float lsS[512], lsQ[512];
    __shared__ float a1s[16], d1s[16], bias2L[256];
    int tid = threadIdx.x, j = blockIdx.y;
    int wav = tid >> 6, lane = tid & 63;
    int quad = lane >> 4, l15 = lane & 15;
    int nh = wav & 1, mp = wav >> 1;
    int b0 = blockIdx.x * 64, m0 = b0 + mp * 32;
    if (tid < 16) {
        float mu  = stats1[tid] * invN1;
        float var = stats1[16 + tid] * invN1 - mu * mu;
        float rs  = rsqrtf(var + EPS);
        a1s[tid] = g1[tid] * rs;
        d1s[tid] = b1[tid] - mu * a1s[tid];
    }
    __syncthreads();
    {   // bias2L[col] = sum_i d1[i]*S[j][i][col], coalesced over col=tid
        float s = 0.f;
        const float* Sj = S + (size_t)j * 4096;
        #pragma unroll
        for (int i = 0; i < 16; ++i) s = fmaf(d1s[i], Sj[i * 256 + tid], s);
        bias2L[tid] = s;
    }
    __syncthreads();                         // bias2L is read cross-thread below
    float biasv[8];
    #pragma unroll
    for (int T = 0; T < 8; ++T) biasv[T] = bias2L[(nh * 8 + T) * 16 + l15];
    floatx4 acc[2][8];
    #pragma unroll
    for (int mi = 0; mi < 2; ++mi)
        #pragma unroll
        for (int T = 0; T < 8; ++T) acc[mi][T] = floatx4{0.f, 0.f, 0.f, 0.f};
    const short8* Bj = (const short8*)W2r + (size_t)(j * 16) * 12 * 64;
    #pragma unroll
    for (int ks = 0; ks < 12; ++ks) {
        int icq = ks * 4 + quad;
        int i = icq / 3, c = icq - i * 3;
        float a1v = a1s[i];
        const unsigned short* ap = p1 + ((size_t)(j + c) * B + m0 + l15) * 128 + i * 8;
        short8 a0 = scale8(*(const short8*)ap, a1v);
        short8 a1 = scale8(*(const short8*)(ap + 2048), a1v);
        #pragma unroll
        for (int T = 0; T < 8; ++T) {
            short8 b = Bj[((nh * 8 + T) * 12 + ks) * 64 + lane];
            acc[0][T] = __builtin_amdgcn_mfma_f32_16x16x32_bf16(a0, b, acc[0][T], 0, 0, 0);
            acc[1][T] = __builtin_amdgcn_mfma_f32_16x16x32_bf16(a1, b, acc[1][T], 0, 0, 0);
        }
    }
    float psum[2] = {0.f, 0.f}, pss[2] = {0.f, 0.f};
    for (int pass = 0; pass < 2; ++pass) {
        __syncthreads();
        if (mp == pass) {
            #pragma unroll
            for (int T = 0; T < 8; ++T) {
                int col = (nh * 8 + T) * 16 + l15;
                #pragma unroll
                for (int mi = 0; mi < 2; ++mi) {
                    int rb = mi * 16 + quad * 4;
                    #pragma unroll
                    for (int r = 0; r < 4; ++r)
                        z[(rb + r) * 260 + col] = acc[mi][T][r] + biasv[T];
                }
            }
        }
        __syncthreads();
        #pragma unroll
        for (int i2 = 0; i2 < 2; ++i2) {
            int u = tid + 256 * i2;
            int opr = u & 15, row = u >> 4;
            const float* zr = &z[row * 260 + opr * 16];
            floatx4 q0 = ((const floatx4*)zr)[0];
            floatx4 q1 = ((const floatx4*)zr)[1];
            floatx4 q2 = ((const floatx4*)zr)[2];
            floatx4 q3 = ((const floatx4*)zr)[3];
            float ta[8] = {q0[0], q0[1], q0[2], q0[3], q1[0], q1[1], q1[2], q1[3]};
            float tb[8] = {q2[0], q2[1], q2[2], q2[3], q3[0], q3[1], q3[2], q3[3]};
            int rowg = pass * 32 + row;
            #pragma unroll
            for (int tp = 0; tp < 4; ++tp) {
                int lo = (tp == 0) ? 0 : 2 * tp - 1;
                int hi = (tp == 3) ? 7 : 2 * tp + 2;
                float m0v = ta[lo], m1v = tb[lo];
                for (int tt = lo + 1; tt <= hi; ++tt) {
                    m0v = fmaxf(m0v, ta[tt]); m1v = fmaxf(m1v, tb[tt]);
                }
                m0v = fmaxf(m0v, 0.f); m1v = fmaxf(m1v, 0.f);
                psum[0] += m0v; pss[0] += m0v * m0v;
                psum[1] += m1v; pss[1] += m1v * m1v;
                unsigned pk = (unsigned)f2bf(m0v) | ((unsigned)f2bf(m1v) << 16);
                *(unsigned*)&pt[tp][rowg][opr * 2] = pk;
            }
        }
    }
    {
        int o0 = 2 * (tid & 15), g = tid >> 4;
        lsS[o0 * 16 + g] = psum[0]; lsS[(o0 + 1) * 16 + g] = psum[1];
        lsQ[o0 * 16 + g] = pss[0];  lsQ[(o0 + 1) * 16 + g] = pss[1];
    }
    __syncthreads();
    #pragma unroll
    for (int tp = 0; tp < 4; ++tp) {
        int oct = tid & 3, row = (tid >> 2) & 63;
        *(short8*)(p2s + ((size_t)(j * 4 + tp) * B + b0 + row) * 32 + oct * 8) =
            *(const short8*)&pt[tp][row][oct * 8];
    }
    if (tid < 64) {
        int o = tid & 31;
        const float* src = (tid < 32) ? lsS : lsQ;
        float s = 0.f;
        #pragma unroll
        for (int g = 0; g < 16; ++g) s += src[o * 16 + g];
        atomicAdd(&stats2[(tid < 32 ? 0 : 32) + o], s);
    }
}

__global__ void __launch_bounds__(256) k3(const unsigned short* __restrict__ p2s,
                                          const float* __restrict__ w3,
                                          const float* __restrict__ g2,
                                          const float* __restrict__ b2,
                                          const float* __restrict__ stats2,
                                          unsigned short* __restrict__ act3,
                                          float* __restrict__ stats3,
                                          float invN2, int B) {
    __shared__ float w3s[6144];
    __shared__ float a2s[32], d2s[32];
    __shared__ unsigned short atile[32][72];
    __shared__ float lsS[1024], lsQ[1024];
    int tid = threadIdx.x, j = blockIdx.y, b0 = blockIdx.x * 32;
    int og = tid >> 6, lane = tid & 63;
    int quad = lane >> 4, l15 = lane & 15;
    #pragma unroll
    for (int u = 0; u < 6; ++u) {            // coalesced preload (24 KB)
        int idx = tid * 4 + u * 1024;
        *(floatx4*)&w3s[idx] = *(const floatx4*)&w3[idx];
    }
    if (tid < 32) {
        float mu  = stats2[tid] * invN2;
        float var = stats2[32 + tid] * invN2 - mu * mu;
        float rs  = rsqrtf(var + EPS);
        a2s[tid] = g2[tid] * rs;
        d2s[tid] = b2[tid] - mu * a2s[tid];
    }
    __syncthreads();
    int o = og * 16 + l15;
    float biasacc = 0.f;
    short8 af[3];
    #pragma unroll
    for (int kf = 0; kf < 3; ++kf) {
        short8 v;
        #pragma unroll
        for (int e = 0; e < 8; ++e) {
            int i = quad * 8 + e;
            float raw = w3s[o * 96 + i * 3 + kf];
            v[e] = (short)f2bf(raw * a2s[i]);
            biasacc = fmaf(raw, d2s[i], biasacc);
        }
        af[kf] = v;
    }
    biasacc += __shfl_xor(biasacc, 16, 64);
    biasacc += __shfl_xor(biasacc, 32, 64);
    float brow[4];
    #pragma unroll
    for (int r = 0; r < 4; ++r) brow[r] = __shfl(biasacc, quad * 4 + r, 64);
    float inv = 1.f / (float)(1 << j);
    float psum[4] = {0.f, 0.f, 0.f, 0.f}, pss[4] = {0.f, 0.f, 0.f, 0.f};
    #pragma unroll
    for (int bt = 0; bt < 2; ++bt) {
        int bb = b0 + bt * 16;
        floatx4 aL0 = {0.f, 0.f, 0.f, 0.f};
        floatx4 aL1 = {0.f, 0.f, 0.f, 0.f};
        floatx4 aL2 = {0.f, 0.f, 0.f, 0.f};
        #pragma unroll
        for (int c = 0; c < 3; ++c) {
            const unsigned short* base =
                p2s + ((size_t)((j + c) * 4) * B + bb + l15) * 32 + quad * 8;
            short8 f0 = *(const short8*)base;
            short8 f1 = *(const short8*)(base + (size_t)B * 32);
            short8 f2v = *(const short8*)(base + (size_t)2 * B * 32);
            aL0 = __builtin_amdgcn_mfma_f32_16x16x32_bf16(af[c], f0, aL0, 0, 0, 0);
            aL1 = __builtin_amdgcn_mfma_f32_16x16x32_bf16(af[c], f1, aL1, 0, 0, 0);
            aL2 = __builtin_amdgcn_mfma_f32_16x16x32_bf16(af[c], f2v, aL2, 0, 0, 0);
        }
        #pragma unroll
        for (int r = 0; r < 4; ++r) {
            float vm = fmaxf(fmaxf(aL0[r], aL1[r]), aL2[r]);
            float v  = fmaxf((vm + brow[r]) * inv, 0.f);
            atile[bt * 16 + l15][og * 16 + quad * 4 + r] = f2bf(v);
            psum[r] += v; pss[r] += v * v;
        }
    }
    #pragma unroll
    for (int r = 0; r < 4; ++r) {
        lsS[(og * 16 + quad * 4 + r) * 16 + l15] = psum[r];
        lsQ[(og * 16 + quad * 4 + r) * 16 + l15] = pss[r];
    }
    __syncthreads();
    {
        int row = tid >> 3, oct = tid & 7;
        *(short8*)(act3 + ((size_t)j * B + b0 + row) * 64 + oct * 8) =
            *(const short8*)&atile[row][oct * 8];
    }
    if (tid < 128) {
        int oo = tid & 63;
        const float* src = (tid < 64) ? lsS : lsQ;
        float s = 0.f;
        #pragma unroll
        for (int g = 0; g < 16; ++g) s += src[oo * 16 + g];
        atomicAdd(&stats3[(tid < 64 ? 0 : 64) + oo], s);
    }
}

__global__ void __launch_bounds__(128) k4(const unsigned short* __restrict__ act3,
                                          const float* __restrict__ g3,
                                          const float* __restrict__ b3,
                                          const float* __restrict__ stats3,
                                          const float* __restrict__ fw1,
                                          const float* __restrict__ fb1,
                                          const float* __restrict__ fw2,
                                          const float* __restrict__ fb2,
                                          const float* __restrict__ fw3,
                                          const float* __restrict__ fb3,
                                          float* __restrict__ out,
                                          float invN3, int B) {
    __shared__ float fw1L[5120];
    __shared__ float a3s[64], d3s[64];
    __shared__ unsigned short W1s[5120];
    __shared__ float fw2s[256], fw3s[272], fb2s[16], fb3s[17], fb1f[16], tmp[4][16];
    __shared__ float hbuf[2][16][17];
    int tid = threadIdx.x;
    int wav = tid >> 6, lane = tid & 63;
    int quad = lane >> 4, l15 = lane & 15;
    #pragma unroll
    for (int u = 0; u < 10; ++u) {           // coalesced fw1 preload (20 KB)
        int idx = (tid + u * 128) * 4;
        *(floatx4*)&fw1L[idx] = *(const floatx4*)&fw1[idx];
    }
    if (tid < 64) {
        float mu  = stats3[tid] * invN3;
        float var = stats3[64 + tid] * invN3 - mu * mu;
        float rs  = rsqrtf(var + EPS);
        a3s[tid] = g3[tid] * rs;
        d3s[tid] = b3[tid] - mu * a3s[tid];
    }
    if (tid < 16) fb2s[tid] = fb2[tid];
    if (tid < 17) fb3s[tid] = fb3[tid];
    #pragma unroll
    for (int u = 0; u < 2; ++u) fw2s[tid + u * 128] = fw2[tid + u * 128];
    for (int idx = tid; idx < 272; idx += 128) fw3s[idx] = fw3[idx];
    __syncthreads();
    #pragma unroll
    for (int u = 0; u < 40; ++u) {
        int idx = tid + u * 128;
        int e  = idx & 7;
        int ln = (idx >> 3) & 63;
        int fs = idx >> 9;
        int jj = fs >> 1, ks = fs & 1;
        int n = ln & 15;
        int oo = ks * 32 + (ln >> 4) * 8 + e;
        W1s[idx] = f2bf(fw1L[n * 320 + oo * 5 + jj] * a3s[oo]);
    }
    if (tid < 64) {
        int f = tid & 15, ch = tid >> 4;
        float s = 0.f;
        for (int u = 0; u < 80; ++u) {
            int n = ch * 80 + u;
            s = fmaf(fw1L[f * 320 + n], d3s[n / 5], s);
        }
        tmp[ch][f] = s;
    }
    __syncthreads();
    if (tid < 16) fb1f[tid] = fb1[tid] + tmp[0][tid] + tmp[1][tid] + tmp[2][tid] + tmp[3][tid];
    __syncthreads();
    int mt = blockIdx.x * 2 + wav;
    floatx4 acc = {0.f, 0.f, 0.f, 0.f};
    #pragma unroll
    for (int jj = 0; jj < 5; ++jj)
        #pragma unroll
        for (int ks = 0; ks < 2; ++ks) {
            short8 a = *(const short8*)(act3 +
                ((size_t)jj * B + mt * 16 + l15) * 64 + ks * 32 + quad * 8);
            short8 b = *(const short8*)&W1s[((jj * 2 + ks) * 64 + lane) * 8];
            acc = __builtin_amdgcn_mfma_f32_16x16x32_bf16(a, b, acc, 0, 0, 0);
        }
    #pragma unroll
    for (int r = 0; r < 4; ++r) hbuf[wav][quad * 4 + r][l15] = acc[r] + fb1f[l15];
    __syncthreads();
    if (lane < 16) {
        int row = l15;
        float hv[16];
        #pragma unroll
        for (int n = 0; n < 16; ++n) hv[n] = hbuf[wav][row][n];
        float h2[16];
        #pragma unroll
        for (int f2 = 0; f2 < 16; ++f2) {
            float s = fb2s[f2];
            #pragma unroll
            for (int n = 0; n < 16; ++n) s = fmaf(fw2s[f2 * 16 + n], hv[n], s);
            h2[f2] = s;
        }
        float* orow = out + (size_t)(mt * 16 + row) * 17;
        #pragma unroll
        for (int f3 = 0; f3 < 17; ++f3) {
            float s = fb3s[f3];
            #pragma unroll
            for (int n = 0; n < 16; ++n) s = fmaf(fw3s[f3 * 16 + n], h2[n], s);
            orow[f3] = s;
        }
    }
}

extern "C" void kernel_launch(void* const* d_in, const int* in_sizes, int n_in,
                              void* d_out, int out_size, void* d_ws, size_t ws_size,
                              hipStream_t stream) {
    (void)n_in; (void)out_size; (void)ws_size;
    const float* x   = (const float*)d_in[0];
    const float* w1  = (const float*)d_in[1];
    const float* w2  = (const float*)d_in[2];
    const float* w3  = (const float*)d_in[3];
    const float* g1  = (const float*)d_in[4];
    const float* b1  = (const float*)d_in[5];
    const float* g2  = (const float*)d_in[6];
    const float* b2  = (const float*)d_in[7];
    const float* g3  = (const float*)d_in[8];
    const float* b3  = (const float*)d_in[9];
    const float* fw1 = (const float*)d_in[10];
    const float* fb1 = (const float*)d_in[11];
    const float* fw2 = (const float*)d_in[12];
    const float* fb2 = (const float*)d_in[13];
    const float* fw3 = (const float*)d_in[14];
    const float* fb3 = (const float*)d_in[15];
    float* out = (float*)d_out;

    int B = in_sizes[0] / 96;                 // 4096

    char* wsb = (char*)d_ws;
    float*          stats = (float*)wsb;                      // 256 f
    unsigned short* W1f   = (unsigned short*)(wsb + 1024);    // 221184 us
    unsigned short* W2r   = W1f + 221184;                     // 688128 us
    float*          S     = (float*)(W2r + 688128);           // 28672 f
    unsigned short* p1    = (unsigned short*)(S + 28672);     // 9*B*128 us
    unsigned short* p2s   = p1 + (size_t)9 * B * 128;         // 28*B*32 us
    unsigned short* act3  = p2s + (size_t)28 * B * 32;        // 5*B*64 us

    float* stats1 = stats;
    float* stats2 = stats + 32;
    float* stats3 = stats + 96;

    float invN1 = 1.f / (float)(B * 72);
    float invN2 = 1.f / (float)(B * 28);
    float invN3 = 1.f / (float)(B * 5);

    kS<<<3665, 256, 0, stream>>>(w1, w2, W1f, W2r, S, stats);
    k1<<<dim3(B / 32, 9), 256, 0, stream>>>(x, W1f, p1, stats1, B);
    k2<<<dim3(B / 64, 7), 256, 0, stream>>>(p1, W2r, S, g1, b1, stats1, p2s, stats2,
                                            invN1, B);
    k3<<<dim3(B / 32, 5), 256, 0, stream>>>(p2s, w3, g2, b2, stats2, act3, stats3,
                                            invN2, B);
    k4<<<B / 32, 128, 0, stream>>>(act3, g3, b3, stats3, fw1, fb1, fw2, fb2, fw3, fb3,
                                   out, invN3, B);
}